// Round 19
// baseline (821.462 us; speedup 1.0000x reference)
//
#include <hip/hip_runtime.h>

#define EPS 1e-5f
typedef unsigned short u16;
typedef short s16x8 __attribute__((ext_vector_type(8)));
typedef float f32x4 __attribute__((ext_vector_type(4)));

__device__ __forceinline__ float siluf(float x) { return x / (1.0f + __expf(-x)); }
__device__ __forceinline__ float geluf(float x) {
    float u = 0.7978845608028654f * (x + 0.044715f * x * x * x);
    return 0.5f * x * (1.0f + tanhf(u));
}
__device__ __forceinline__ u16 f2bf(float f) {
    unsigned u = __float_as_uint(f);
    return (u16)((u + 0x7fffu + ((u >> 16) & 1u)) >> 16);
}
__device__ __forceinline__ float bf2f(u16 v) {
    return __uint_as_float(((unsigned)v) << 16);
}
struct u16x4 { u16 x, y, z, w; };
__device__ __forceinline__ u16x4 f2bf4(float4 v) {
    u16x4 r; r.x = f2bf(v.x); r.y = f2bf(v.y); r.z = f2bf(v.z); r.w = f2bf(v.w);
    return r;
}

#define GLOAD_LDS16(gp, lp) __builtin_amdgcn_global_load_lds( \
    (const __attribute__((address_space(1))) void*)(gp),      \
    (__attribute__((address_space(3))) void*)(lp), 16, 0, 0)

// ---------------- merged weight casts (one dispatch) ----------------
__global__ void k_casts(const float* __restrict__ ip, const float* __restrict__ op,
                        const float* __restrict__ inp, u16* __restrict__ wip,
                        u16* __restrict__ wop, u16* __restrict__ winp) {
    int idx = blockIdx.x * 256 + threadIdx.x;   // 1835008 total
    if (idx < 1245184) {                        // in_proj, zero-pad rows >= 2320
        int e4 = idx * 4;
        int layer = e4 / 1245184;
        int rem   = e4 - layer * 1245184;
        int row   = rem >> 9;
        int k     = rem & 511;
        float4 v = make_float4(0.f, 0.f, 0.f, 0.f);
        if (row < 2320)
            v = *(const float4*)(ip + (size_t)layer * 1187840 + (size_t)row * 512 + k);
        *(u16x4*)(wip + e4) = f2bf4(v);
    } else if (idx < 1245184 + 524288) {        // out_proj
        int j = idx - 1245184;
        float4 v = *(const float4*)(op + (size_t)j * 4);
        *(u16x4*)(wop + (size_t)j * 4) = f2bf4(v);
    } else if (idx < 1245184 + 524288 + 65536) {  // inp
        int j = idx - 1245184 - 524288;
        float4 v = *(const float4*)(inp + (size_t)j * 4);
        *(u16x4*)(winp + (size_t)j * 4) = f2bf4(v);
    }
}

// ---------------- embedding + positional -> bf16 ----------------
__global__ void k_embed(const int* __restrict__ tok, const float* __restrict__ emb,
                        const float* __restrict__ pos, u16* __restrict__ out) {
    int idx = blockIdx.x * 256 + threadIdx.x;   // over 8192*512/4 = 1048576
    int d4 = idx & 127;
    int bl = idx >> 7;
    int l  = bl & 1023;
    float4 e = *(const float4*)(emb + tok[bl] * 512 + d4 * 4);
    float4 p = *(const float4*)(pos + l * 512 + d4 * 4);
    float4 v = make_float4(e.x + p.x, e.y + p.y, e.z + p.z, e.w + p.w);
    *(u16x4*)(out + (size_t)idx * 4) = f2bf4(v);
}

// ===== in_proj GEMM: 256x128 tile, 512 thr, wave-tile 64x64, 3-buf depth-2 ====
#define STAGE_I(buf, k0) do {                                                   \
    _Pragma("unroll")                                                           \
    for (int s_ = 0; s_ < 2; s_++) {                                            \
        int g_ = w * 2 + s_;                                                    \
        GLOAD_LDS16(A + (size_t)(m0 + g_ * 16 + lr) * 512 + (k0) + lk,          \
                    smem + (buf) * 8192 + g_ * 512);                            \
    }                                                                           \
    GLOAD_LDS16(B + (size_t)(n0 + w * 16 + lr) * 512 + (k0) + lk,               \
                smem + 24576 + (buf) * 4096 + w * 512);                         \
    } while (0)

#define COMPUTE_I(buf) do {                                                     \
    s16x8 af_[4], bf_[4];                                                       \
    _Pragma("unroll")                                                           \
    for (int i_ = 0; i_ < 4; i_++) {                                            \
        af_[i_] = *(const s16x8*)&smem[(buf) * 8192 + (wr * 4 + i_) * 512 + l * 8]; \
        bf_[i_] = *(const s16x8*)&smem[24576 + (buf) * 4096 + (wc * 4 + i_) * 512 + l * 8]; \
    }                                                                           \
    _Pragma("unroll")                                                           \
    for (int i_ = 0; i_ < 4; i_++)                                              \
        _Pragma("unroll")                                                       \
        for (int j_ = 0; j_ < 4; j_++)                                          \
            acc[i_][j_] = __builtin_amdgcn_mfma_f32_16x16x32_bf16(              \
                af_[i_], bf_[j_], acc[i_][j_], 0, 0, 0);                        \
    } while (0)

__global__ __launch_bounds__(512, 4) void k_gemm_in(
    const u16* __restrict__ A, const u16* __restrict__ B,
    u16* __restrict__ zbf, u16* __restrict__ xbcbf, float* __restrict__ dtw) {
    __shared__ __align__(16) u16 smem[36864];   // 3x8192 A | 3x4096 B; ep 256x136
    const int t = threadIdx.x;
    const int w = t >> 6, l = t & 63;
    const int wr = w >> 1, wc = w & 1;          // 4x2 wave grid, wave-tile 64x64
    const int lr = l & 15, lk = (l >> 4) * 8;
    const int wgid = (blockIdx.x & 7) * 76 + (blockIdx.x >> 3);  // 608 = 8*76
    const int m0 = (wgid / 19) * 256;
    const int nt = wgid % 19;
    const int n0 = nt * 128;

    f32x4 acc[4][4] = {};

    STAGE_I(0, 0);
    STAGE_I(1, 32);
    for (int ki = 0; ki < 14; ki++) {           // nk = 16
        asm volatile("s_waitcnt vmcnt(3)" ::: "memory");
        __builtin_amdgcn_s_barrier();
        STAGE_I((ki + 2) % 3, (ki + 2) * 32);
        COMPUTE_I(ki % 3);
    }
    asm volatile("s_waitcnt vmcnt(3)" ::: "memory");
    __builtin_amdgcn_s_barrier();
    COMPUTE_I(14 % 3);
    asm volatile("s_waitcnt vmcnt(0)" ::: "memory");
    __builtin_amdgcn_s_barrier();
    COMPUTE_I(15 % 3);
    __syncthreads();

    if (nt < 18) {
        // repack to LDS (bf16), then coalesced u16x8 stores
#pragma unroll
        for (int i = 0; i < 4; i++)
#pragma unroll
            for (int j = 0; j < 4; j++)
#pragma unroll
                for (int r2 = 0; r2 < 4; r2++) {
                    int erow = wr * 64 + i * 16 + (l >> 4) * 4 + r2;
                    int ecol = wc * 64 + j * 16 + (l & 15);
                    smem[erow * 136 + ecol] = f2bf(acc[i][j][r2]);
                }
        __syncthreads();
        if (nt < 8) {
#pragma unroll
            for (int it = 0; it < 8; it++) {
                int v = it * 512 + t;
                int row = v >> 4, col = (v & 15) * 8;
                *(s16x8*)&zbf[(size_t)(m0 + row) * 1024 + n0 + col] =
                    *(const s16x8*)&smem[row * 136 + col];
            }
        } else {
            int nb = n0 - 1024;
#pragma unroll
            for (int it = 0; it < 8; it++) {
                int v = it * 512 + t;
                int row = v >> 4, col = (v & 15) * 8;
                *(s16x8*)&xbcbf[(size_t)(m0 + row) * 1280 + nb + col] =
                    *(const s16x8*)&smem[row * 136 + col];
            }
        }
    } else {
        // dt tile (cols 2304..2319 live, rest zero-pad)
#pragma unroll
        for (int i = 0; i < 4; i++) {
            int mb = m0 + wr * 64 + i * 16 + (l >> 4) * 4;
#pragma unroll
            for (int j = 0; j < 4; j++) {
                int n = n0 + wc * 64 + j * 16 + (l & 15);
#pragma unroll
                for (int r2 = 0; r2 < 4; r2++) {
                    if (n < 2320)
                        dtw[(size_t)(mb + r2) * 16 + (n - 2304)] = acc[i][j][r2];
                }
            }
        }
    }
}

// --- generic MFMA GEMM NT: 512 thr, wave-tile 64x32, 3-buf depth-2 -----------
// MODE 1: C = acc + bias[n] (f32)
// MODE 2: Cbf = bf16((bf2f(Cbf) + acc) * mask[m])   (bf16 residual RMW)
#define STAGE(buf, k0) do {                                                     \
    GLOAD_LDS16(A + (size_t)(m0 + w * 16 + lr) * K + (k0) + lk,                 \
                &Asm[buf][w * 512]);                                            \
    GLOAD_LDS16(B + (size_t)(n0 + w * 16 + lr) * K + (k0) + lk,                 \
                &Bsm[buf][w * 512]);                                            \
    } while (0)

#define COMPUTE(buf) do {                                                       \
    s16x8 af_[4], bf_[2];                                                       \
    _Pragma("unroll")                                                           \
    for (int i_ = 0; i_ < 4; i_++)                                              \
        af_[i_] = *(const s16x8*)&Asm[buf][(wr * 4 + i_) * 512 + l * 8];        \
    _Pragma("unroll")                                                           \
    for (int j_ = 0; j_ < 2; j_++)                                              \
        bf_[j_] = *(const s16x8*)&Bsm[buf][(wc * 2 + j_) * 512 + l * 8];        \
    _Pragma("unroll")                                                           \
    for (int i_ = 0; i_ < 4; i_++)                                              \
        _Pragma("unroll")                                                       \
        for (int j_ = 0; j_ < 2; j_++)                                          \
            acc[i_][j_] = __builtin_amdgcn_mfma_f32_16x16x32_bf16(              \
                af_[i_], bf_[j_], acc[i_][j_], 0, 0, 0);                        \
    } while (0)

template <int MODE>
__global__ __launch_bounds__(512) void k_gemm_mfma(
    const u16* __restrict__ A, const u16* __restrict__ B,
    const float* __restrict__ bias, float* __restrict__ C,
    u16* __restrict__ Cbf, const float* __restrict__ mask,
    int M, int N, int K, int gx) {
    __shared__ u16 Asm[3][4096];
    __shared__ u16 Bsm[3][4096];
    const int t = threadIdx.x;
    const int w = t >> 6, l = t & 63;
    const int wr = w >> 2, wc = w & 3;          // 2x4 wave grid, wave-tile 64x32
    const int lr = l & 15, lk = (l >> 4) * 8;
    const int nwg = gridDim.x;
    const int q = nwg >> 3, r = nwg & 7;
    const int x8 = blockIdx.x & 7, d8 = blockIdx.x >> 3;
    const int wgid = (x8 < r) ? x8 * (q + 1) + d8 : r * (q + 1) + (x8 - r) * q + d8;
    const int m0 = (wgid / gx) * 128;
    const int n0 = (wgid % gx) * 128;

    f32x4 acc[4][2] = {};

    const int nk = K >> 5;
    STAGE(0, 0);
    STAGE(1, 32);
    for (int ki = 0; ki < nk - 2; ki++) {
        asm volatile("s_waitcnt vmcnt(2)" ::: "memory");
        __builtin_amdgcn_s_barrier();
        STAGE((ki + 2) % 3, (ki + 2) * 32);
        COMPUTE(ki % 3);
    }
    asm volatile("s_waitcnt vmcnt(2)" ::: "memory");
    __builtin_amdgcn_s_barrier();
    COMPUTE((nk - 2) % 3);
    asm volatile("s_waitcnt vmcnt(0)" ::: "memory");
    __builtin_amdgcn_s_barrier();
    COMPUTE((nk - 1) % 3);

#pragma unroll
    for (int i = 0; i < 4; i++) {
        int mb = m0 + wr * 64 + i * 16 + (l >> 4) * 4;
#pragma unroll
        for (int j = 0; j < 2; j++) {
            int n = n0 + wc * 32 + j * 16 + (l & 15);
#pragma unroll
            for (int r2 = 0; r2 < 4; r2++) {
                int m = mb + r2;
                float v = acc[i][j][r2];
                if (n < N) {
                    size_t o = (size_t)m * N + n;
                    if (MODE == 1) {
                        C[o] = v + bias[n];
                    } else {
                        float v2 = (bf2f(Cbf[o]) + v) * mask[m];
                        Cbf[o] = f2bf(v2);
                    }
                }
            }
        }
    }
}

// ---------------- LayerNorm + mask -> bf16 only ----------------
__global__ __launch_bounds__(128) void k_layernorm(
    const float* __restrict__ x, const float* __restrict__ g,
    const float* __restrict__ b, const float* __restrict__ mask,
    u16* __restrict__ xbf) {
    __shared__ float2 sbuf[2];
    int bl = blockIdx.x;
    int t  = threadIdx.x;
    float4 v = *(const float4*)(x + (size_t)bl * 512 + t * 4);
    float s = v.x + v.y + v.z + v.w;
    float q = v.x * v.x + v.y * v.y + v.z * v.z + v.w * v.w;
    for (int off = 32; off; off >>= 1) {
        s += __shfl_xor(s, off, 64);
        q += __shfl_xor(q, off, 64);
    }
    int wid = t >> 6, lane = t & 63;
    if (lane == 0) sbuf[wid] = make_float2(s, q);
    __syncthreads();
    float ts = sbuf[0].x + sbuf[1].x;
    float tq = sbuf[0].y + sbuf[1].y;
    float mu  = ts * (1.f / 512.f);
    float var = tq * (1.f / 512.f) - mu * mu;
    float inv = 1.0f / sqrtf(var + EPS);
    float mk  = mask[bl];
    float4 gg = *(const float4*)(g + t * 4);
    float4 bb = *(const float4*)(b + t * 4);
    float4 o;
    o.x = ((v.x - mu) * inv * gg.x + bb.x) * mk;
    o.y = ((v.y - mu) * inv * gg.y + bb.y) * mk;
    o.z = ((v.z - mu) * inv * gg.z + bb.z) * mk;
    o.w = ((v.w - mu) * inv * gg.w + bb.w) * mk;
    *(u16x4*)(xbf + (size_t)bl * 512 + t * 4) = f2bf4(o);
}

// --- causal depthwise conv (k=4, bf16 in) + bias + SiLU -> bf16 (xh | B/C) ---
__global__ __launch_bounds__(320) void k_conv(
    const u16* __restrict__ xbc_in, const float* __restrict__ cw,
    const float* __restrict__ cb, u16* __restrict__ xhbf,
    u16* __restrict__ bcbf) {
    int bid = blockIdx.x;
    int bl = (bid & 7) * 1024 + (bid >> 3);    // 8192 rows, bijective
    int l  = bl & 1023;
    int c  = threadIdx.x * 4;
    float4 w0 = *(const float4*)(cw + (c + 0) * 4);
    float4 w1 = *(const float4*)(cw + (c + 1) * 4);
    float4 w2 = *(const float4*)(cw + (c + 2) * 4);
    float4 w3 = *(const float4*)(cw + (c + 3) * 4);
    float4 a  = *(const float4*)(cb + c);
#pragma unroll
    for (int k = 0; k < 4; k++) {
        if (l + k - 3 >= 0) {
            u16x4 v = *(const u16x4*)(xbc_in + (size_t)(bl + k - 3) * 1280 + c);
            const float* wk0 = (const float*)&w0;
            const float* wk1 = (const float*)&w1;
            const float* wk2 = (const float*)&w2;
            const float* wk3 = (const float*)&w3;
            a.x = fmaf(bf2f(v.x), wk0[k], a.x);
            a.y = fmaf(bf2f(v.y), wk1[k], a.y);
            a.z = fmaf(bf2f(v.z), wk2[k], a.z);
            a.w = fmaf(bf2f(v.w), wk3[k], a.w);
        }
    }
    float4 o = make_float4(siluf(a.x), siluf(a.y), siluf(a.z), siluf(a.w));
    if (c < 1024)
        *(u16x4*)(xhbf + (size_t)bl * 1024 + c) = f2bf4(o);
    else
        *(u16x4*)(bcbf + (size_t)bl * 256 + (c - 1024)) = f2bf4(o);
}

// ============ fused SSD intra (T14 early xh prefetch; T5 setprio) ============
#define SSD_STAGE(dst, k0) do {                                                 \
    _Pragma("unroll")                                                           \
    for (int s_ = 0; s_ < 2; s_++) {                                            \
        int g_ = w * 2 + s_;                                                    \
        GLOAD_LDS16(bcbf + (row0 + g_ * 16 + lr) * 256 + 128 + (k0) + lk8,      \
                    (dst) + g_ * 512);                                          \
        GLOAD_LDS16(bcbf + (row0 + g_ * 16 + lr) * 256 + (k0) + lk8,            \
                    (dst) + 4096 + g_ * 512);                                   \
    } } while (0)

__global__ __launch_bounds__(256) void k_ssd(
    const u16* __restrict__ xhbf, const u16* __restrict__ bcbf,
    const float* __restrict__ dt_raw, const float* __restrict__ dtbias,
    const float* __restrict__ alog, float* __restrict__ elbuf,
    u16* __restrict__ y16, u16* __restrict__ scb16) {
    int bid = blockIdx.x;
    int bhc = (bid & 7) * 128 + (bid >> 3);   // bijective; batch b stays on one XCD
    int c = bhc & 7, h = (bhc >> 3) & 15, b = bhc >> 7;
    const size_t row0 = (size_t)b * 1024 + c * 128;
    const int t = threadIdx.x, w = t >> 6, l = t & 63;
    const int wr = w >> 1, wc = w & 1;
    const int lr = l & 15, lk8 = (l >> 4) * 8;

    __shared__ float cl[128], dtl[128], wv[128];
    __shared__ float csh;
    __shared__ __align__(16) u16 shA[8704];
    __shared__ __align__(16) u16 shB[17408];

    // T14: issue UT's xh global loads EARLY — they retire under cumsum+phase1.
    // vmcnt safety: these are issued (and pinned by the asm "memory" clobbers)
    // before the stage loads, so every counted vmcnt(4) still guarantees the
    // needed stage buffer has landed; xpre is consumed only after vmcnt(0).
    const int utj = t >> 1;                    // 0..127
    const int utp = (t & 1) * 32;              // p half
    s16x8 xpre0, xpre1, xpre2, xpre3;
    {
        const u16* src = xhbf + (row0 + utj) * 1024 + h * 64 + utp;
        xpre0 = *(const s16x8*)(src);
        xpre1 = *(const s16x8*)(src + 8);
        xpre2 = *(const s16x8*)(src + 16);
        xpre3 = *(const s16x8*)(src + 24);
    }

    // early scalar loads, then issue phase-1 stages (DMA hides under cumsum)
    float dtb_h = dtbias[h];
    float A = -__expf(alog[h]);
    float raw = 0.f;
    if (t < 128) raw = dt_raw[(row0 + t) * 16 + h] + dtb_h;
    SSD_STAGE(shA, 0);
    SSD_STAGE(shB, 32);

    float v = 0.f;
    if (t < 128) {
        float s = (raw > 20.f) ? raw : log1pf(__expf(raw));
        dtl[t] = s;
        v = s * A;
        int lane = t & 63;
#pragma unroll
        for (int off = 1; off < 64; off <<= 1) {
            float o = __shfl_up(v, off, 64);
            if (lane >= off) v += o;
        }
        if (t == 63) csh = v;
    }
    __syncthreads();
    if (t >= 64 && t < 128) v += csh;
    if (t < 128) {
        cl[t] = v;
        elbuf[(size_t)bhc * 128 + t] = __expf(v);
    }
    __syncthreads();
    if (t < 128) wv[t] = __expf(cl[127] - cl[t]);

    // ---- phase 1: S = C.B^T (2-buf ping-pong, counted vmcnt, setprio MFMA)
    f32x4 acc[4][4] = {};
    for (int ks = 0; ks < 4; ks++) {
        u16* cur = (ks & 1) ? shB : shA;
        if (ks < 3) asm volatile("s_waitcnt vmcnt(4)" ::: "memory");
        else        asm volatile("s_waitcnt vmcnt(0)" ::: "memory");
        __builtin_amdgcn_s_barrier();
        s16x8 af[4], bfr[4];
#pragma unroll
        for (int i = 0; i < 4; i++) {
            af[i]  = *(const s16x8*)&cur[(wr * 4 + i) * 512 + l * 8];
            bfr[i] = *(const s16x8*)&cur[4096 + (wc * 4 + i) * 512 + l * 8];
        }
        __builtin_amdgcn_s_setprio(1);
#pragma unroll
        for (int i = 0; i < 4; i++)
#pragma unroll
            for (int j = 0; j < 4; j++)
                acc[i][j] = __builtin_amdgcn_mfma_f32_16x16x32_bf16(af[i], bfr[j], acc[i][j], 0, 0, 0);
        __builtin_amdgcn_s_setprio(0);
        __builtin_amdgcn_s_barrier();
        if (ks + 2 < 4) SSD_STAGE(cur, (ks + 2) * 32);
    }

    // ---- UT build from prefetched registers: UT[p][j] = dt[j]*x[j][p]
    {
        float dj = dtl[utj];
#pragma unroll
        for (int i = 0; i < 8; i++)
            shA[(utp + 0 + i) * 136 + utj] = f2bf(dj * bf2f((u16)xpre0[i]));
#pragma unroll
        for (int i = 0; i < 8; i++)
            shA[(utp + 8 + i) * 136 + utj] = f2bf(dj * bf2f((u16)xpre1[i]));
#pragma unroll
        for (int i = 0; i < 8; i++)
            shA[(utp + 16 + i) * 136 + utj] = f2bf(dj * bf2f((u16)xpre2[i]));
#pragma unroll
        for (int i = 0; i < 8; i++)
            shA[(utp + 24 + i) * 136 + utj] = f2bf(dj * bf2f((u16)xpre3[i]));
    }
    __syncthreads();

    // ---- phase 2: y = P.U  (P in 64-col halves)
    f32x4 acc2[4][2] = {};
    for (int half = 0; half < 2; half++) {
        if (wc == half) {
#pragma unroll
            for (int i = 0; i < 4; i++) {
#pragma unroll
                for (int j = 0; j < 4; j++) {
                    int col = half * 64 + j * 16 + (l & 15);
#pragma unroll
                    for (int r = 0; r < 4; r++) {
                        int row = wr * 64 + i * 16 + (l >> 4) * 4 + r;
                        float e = __expf(fminf(cl[row] - cl[col], 0.f));
                        float pv = (col <= row) ? acc[i][j][r] * e : 0.f;
                        shB[row * 72 + j * 16 + (l & 15)] = f2bf(pv);
                    }
                }
            }
        }
        __syncthreads();
        __builtin_amdgcn_s_setprio(1);
#pragma unroll
        for (int ks = 0; ks < 2; ks++) {
            int kof = ks * 32;
            s16x8 pa[4], ub[2];
#pragma unroll
            for (int i = 0; i < 4; i++)
                pa[i] = *(const s16x8*)&shB[(wr * 64 + i * 16 + lr) * 72 + kof + lk8];
#pragma unroll
            for (int jj = 0; jj < 2; jj++)
                ub[jj] = *(const s16x8*)&shA[(wc * 32 + jj * 16 + lr) * 136 + half * 64 + kof + lk8];
#pragma unroll
            for (int i = 0; i < 4; i++)
#pragma unroll
                for (int jj = 0; jj < 2; jj++)
                    acc2[i][jj] = __builtin_amdgcn_mfma_f32_16x16x32_bf16(pa[i], ub[jj], acc2[i][jj], 0, 0, 0);
        }
        __builtin_amdgcn_s_setprio(0);
        __syncthreads();
    }

    // ---- y_intra store: f32 repack in shB, then vector u16x8 stores
    {
        float* fb = (float*)shB;   // 128 x 68 f32 = 34816 B = sizeof(shB)
#pragma unroll
        for (int i = 0; i < 4; i++)
#pragma unroll
            for (int jj = 0; jj < 2; jj++)
#pragma unroll
                for (int r = 0; r < 4; r++) {
                    int row = wr * 64 + i * 16 + (l >> 4) * 4 + r;
                    fb[row * 68 + wc * 32 + jj * 16 + (l & 15)] = acc2[i][jj][r];
                }
        __syncthreads();
#pragma unroll
        for (int it = 0; it < 4; it++) {
            int vv = it * 256 + t;            // 128*64/8 = 1024 vectors
            int row = vv >> 3, col = (vv & 7) * 8;
            float4 f0 = *(const float4*)&fb[row * 68 + col];
            float4 f1 = *(const float4*)&fb[row * 68 + col + 4];
            s16x8 ov;
            const float* p0 = (const float*)&f0;
            const float* p1 = (const float*)&f1;
#pragma unroll
            for (int j = 0; j < 4; j++) { ov[j] = (short)f2bf(p0[j]); ov[4 + j] = (short)f2bf(p1[j]); }
            *(s16x8*)&y16[(row0 + row) * 1024 + h * 64 + col] = ov;
        }
        __syncthreads();
    }

    // ---- BTw build: BTw[n][j] = wv[j]*B[j][n]; vectorized u16x8 global reads
    {
        int j = t >> 1;                        // 0..127
        int nh = (t & 1) * 64;                 // n half
        float wj = wv[j];
        const u16* src = bcbf + (row0 + j) * 256 + nh;
#pragma unroll
        for (int vq = 0; vq < 8; vq++) {
            s16x8 vec = *(const s16x8*)(src + vq * 8);
            int n0 = nh + vq * 8;
#pragma unroll
            for (int i = 0; i < 8; i++)
                shB[(n0 + i) * 136 + j] = f2bf(wj * bf2f((u16)vec[i]));
        }
    }
    __syncthreads();

    // ---- phase 3: Sc = UT.(BTw) -> bf16 [p][128]
    f32x4 acc3[4][2] = {};
    __builtin_amdgcn_s_setprio(1);
#pragma unroll
    for (int ks = 0; ks < 4; ks++) {
        int kof = ks * 32;
        s16x8 ua[4], bb[2];
#pragma unroll
        for (int i = 0; i < 4; i++)
            ua[i] = *(const s16x8*)&shA[(i * 16 + lr) * 136 + kof + lk8];
#pragma unroll
        for (int jj = 0; jj < 2; jj++)
            bb[jj] = *(const s16x8*)&shB[(w * 32 + jj * 16 + lr) * 136 + kof + lk8];
#pragma unroll
        for (int i = 0; i < 4; i++)
#pragma unroll
            for (int jj = 0; jj < 2; jj++)
                acc3[i][jj] = __builtin_amdgcn_mfma_f32_16x16x32_bf16(ua[i], bb[jj], acc3[i][jj], 0, 0, 0);
    }
    __builtin_amdgcn_s_setprio(0);
#pragma unroll
    for (int i = 0; i < 4; i++)
#pragma unroll
        for (int jj = 0; jj < 2; jj++) {
            int n = w * 32 + jj * 16 + (l & 15);
#pragma unroll
            for (int r = 0; r < 4; r++) {
                int p = i * 16 + (l >> 4) * 4 + r;
                scb16[(size_t)bhc * 8192 + (size_t)p * 128 + n] = f2bf(acc3[i][jj][r]);
            }
        }
}

// sequential chunk-state recurrence (bf16 in/out, f32 accumulate)
__global__ __launch_bounds__(512) void k_states(u16* __restrict__ scb16,
                                                const float* __restrict__ elbuf) {
    int bh = blockIdx.x;                  // b*16+h
    int t = threadIdx.x;
    float hreg[16];
#pragma unroll
    for (int j = 0; j < 16; j++) hreg[j] = 0.f;
    size_t o = (size_t)t * 16;
    for (int c = 0; c < 8; c++) {
        int bhc = bh * 8 + c;
        float Tc = elbuf[(size_t)bhc * 128 + 127];
        u16* p = scb16 + (size_t)bhc * 8192 + o;
        s16x8 v0 = *(s16x8*)(p);
        s16x8 v1 = *(s16x8*)(p + 8);
        s16x8 o0, o1;
#pragma unroll
        for (int j = 0; j < 8; j++) {
            o0[j] = (short)f2bf(hreg[j]);
            o1[j] = (short)f2bf(hreg[8 + j]);
        }
        *(s16x8*)(p)     = o0;
        *(s16x8*)(p + 8) = o1;
#pragma unroll
        for (int j = 0; j < 8; j++) {
            hreg[j]     = fmaf(Tc, hreg[j],     bf2f((u16)v0[j]));
            hreg[8 + j] = fmaf(Tc, hreg[8 + j], bf2f((u16)v1[j]));
        }
    }
}

// ============ inter-chunk: pipelined stages + vector RMW epilogue ============
#define INT_STAGE(bf_, k0_) do {                                                \
    _Pragma("unroll")                                                           \
    for (int s_ = 0; s_ < 2; s_++) {                                            \
        int g_ = w * 2 + s_;                                                    \
        GLOAD_LDS16(bcbf + (row0 + g_ * 16 + lr) * 256 + 128 + (k0_) + lk8,     \
                    &CStg[bf_][g_ * 512]);                                      \
    }                                                                           \
    GLOAD_LDS16(scb16 + (size_t)bhc * 8192 + (size_t)(w * 16 + lr) * 128 + (k0_) + lk8, \
                &HStg[bf_][w * 512]);                                           \
    } while (0)

__global__ __launch_bounds__(256) void k_inter(
    const u16* __restrict__ xhbf, const u16* __restrict__ bcbf,
    const float* __restrict__ elbuf, const u16* __restrict__ scb16,
    const float* __restrict__ Dp, u16* __restrict__ y16) {
    int bid = blockIdx.x;
    int bhc = (bid & 7) * 128 + (bid >> 3);
    int c = bhc & 7, h = (bhc >> 3) & 15, b = bhc >> 7;
    const size_t row0 = (size_t)b * 1024 + c * 128;
    const int t = threadIdx.x, w = t >> 6, l = t & 63;
    const int wr = w >> 1, wc = w & 1;
    const int lr = l & 15, lk8 = (l >> 4) * 8;
    __shared__ __align__(16) u16 CStg[2][4096];
    __shared__ __align__(16) u16 HStg[2][2048];
    __shared__ __align__(16) float FY[64 * 68];
    __shared__ float el[128];
    float Dv = Dp[h];
    float elv = (t < 128) ? elbuf[(size_t)bhc * 128 + t] : 0.f;

    INT_STAGE(0, 0);
    INT_STAGE(1, 32);
    if (t < 128) el[t] = elv;

    f32x4 acc[4][2] = {};
    for (int ks = 0; ks < 4; ks++) {
        int cur = ks & 1;
        if (ks < 3) asm volatile("s_waitcnt vmcnt(3)" ::: "memory");
        else        asm volatile("s_waitcnt vmcnt(0)" ::: "memory");
        __builtin_amdgcn_s_barrier();
        s16x8 ca[4], hb[2];
#pragma unroll
        for (int i = 0; i < 4; i++)
            ca[i] = *(const s16x8*)&CStg[cur][(wr * 4 + i) * 512 + l * 8];
#pragma unroll
        for (int jj = 0; jj < 2; jj++)
            hb[jj] = *(const s16x8*)&HStg[cur][(wc * 2 + jj) * 512 + l * 8];
        __builtin_amdgcn_s_setprio(1);
#pragma unroll
        for (int i = 0; i < 4; i++)
#pragma unroll
            for (int jj = 0; jj < 2; jj++)
                acc[i][jj] = __builtin_amdgcn_mfma_f32_16x16x32_bf16(ca[i], hb[jj], acc[i][jj], 0, 0, 0);
        __builtin_amdgcn_s_setprio(0);
        __builtin_amdgcn_s_barrier();
        if (ks + 2 < 4) INT_STAGE(cur, (ks + 2) * 32);
    }

    // epilogue: chunked f32 repack (rows ch*64..) -> vector RMW
    for (int ch = 0; ch < 2; ch++) {
        if (wr == ch) {
#pragma unroll
            for (int i = 0; i < 4; i++)
#pragma unroll
                for (int jj = 0; jj < 2; jj++)
#pragma unroll
                    for (int r = 0; r < 4; r++) {
                        int rrow = i * 16 + (l >> 4) * 4 + r;   // 0..63
                        FY[rrow * 68 + wc * 32 + jj * 16 + (l & 15)] =
                            el[ch * 64 + rrow] * acc[i][jj][r];
                    }
        }
        __syncthreads();
#pragma unroll
        for (int it = 0; it < 2; it++) {
            int vv = it * 256 + t;            // 64*64/8 = 512 vectors
            int row = vv >> 3, col = (vv & 7) * 8;
            float4 f0 = *(const float4*)&FY[row * 68 + col];
            float4 f1 = *(const float4*)&FY[row * 68 + col + 4];
            size_t yo = (row0 + ch * 64 + row) * 1024 + h * 64 + col;
            s16x8 yv = *(const s16x8*)&y16[yo];
            s16x8 xv = *(const s16x8*)&xhbf[yo];
            s16x8 ov;
            const float* p0 = (const float*)&f0;
            const float* p1 = (const float*)&f1;
#pragma unroll
            for (int j = 0; j < 4; j++) {
                ov[j]     = (short)f2bf(bf2f((u16)yv[j])     + p0[j] + Dv * bf2f((u16)xv[j]));
                ov[4 + j] = (short)f2bf(bf2f((u16)yv[4 + j]) + p1[j] + Dv * bf2f((u16)xv[4 + j]));
            }
            *(s16x8*)&y16[yo] = ov;
        }
        __syncthreads();
    }
}

// ---------------- gate: ybf = bf16(rmsnorm(y * silu(z)) * norm_w) ----------------
__global__ __launch_bounds__(256) void k_gate(
    const u16* __restrict__ y16, const u16* __restrict__ zbf,
    const float* __restrict__ nw, u16* __restrict__ ybf) {
    __shared__ float sbuf[4];
    int bl = blockIdx.x;
    int t  = threadIdx.x;
    u16x4 yv4 = *(const u16x4*)(y16 + (size_t)bl * 1024 + t * 4);
    u16x4 zv4 = *(const u16x4*)(zbf + (size_t)bl * 1024 + t * 4);
    float4 gv;
    gv.x = bf2f(yv4.x) * siluf(bf2f(zv4.x));
    gv.y = bf2f(yv4.y) * siluf(bf2f(zv4.y));
    gv.z = bf2f(yv4.z) * siluf(bf2f(zv4.z));
    gv.w = bf2f(yv4.w) * siluf(bf2f(zv4.w));
    float q = gv.x * gv.x + gv.y * gv.y + gv.z * gv.z + gv.w * gv.w;
    for (int off = 32; off; off >>= 1) q += __shfl_xor(q, off, 64);
    int wid = t >> 6, lane = t & 63;
    if (lane == 0) sbuf[wid] = q;
    __syncthreads();
    float tot = sbuf[0] + sbuf[1] + sbuf[2] + sbuf[3];
    float scale = 1.0f / sqrtf(tot * (1.f / 1024.f) + EPS);
    float4 nv = *(const float4*)(nw + t * 4);
    float4 o;
    o.x = gv.x * scale * nv.x;
    o.y = gv.y * scale * nv.y;
    o.z = gv.z * scale * nv.z;
    o.w = gv.w * scale * nv.w;
    *(u16x4*)(ybf + (size_t)bl * 1024 + t * 4) = f2bf4(o);
}

// ---------------- pool stage 1 (bf16 input) ----------------
__global__ __launch_bounds__(256) void k_pool1(const u16* __restrict__ xbf,
                                               float* __restrict__ psum,
                                               float* __restrict__ pmax) {
    int blk = blockIdx.x;          // b*64 + lc
    int b = blk >> 6, lc = blk & 63;
    int t = threadIdx.x;
    const u16* px = xbf + (size_t)b * 524288 + (size_t)lc * 16 * 512;
    float s0 = 0.f, s1 = 0.f, m0 = -3.0e38f, m1 = -3.0e38f;
#pragma unroll
    for (int r = 0; r < 16; r++) {
        float v0 = bf2f(px[r * 512 + t]);
        float v1 = bf2f(px[r * 512 + t + 256]);
        s0 += v0; s1 += v1;
        m0 = fmaxf(m0, v0); m1 = fmaxf(m1, v1);
    }
    psum[(size_t)blk * 512 + t]       = s0;
    psum[(size_t)blk * 512 + t + 256] = s1;
    pmax[(size_t)blk * 512 + t]       = m0;
    pmax[(size_t)blk * 512 + t + 256] = m1;
}

// ---------------- pool stage 2 ----------------
__global__ __launch_bounds__(256) void k_pool2(const float* __restrict__ psum,
                                               const float* __restrict__ pmax,
                                               float* __restrict__ pooled) {
    int idx = blockIdx.x * 256 + threadIdx.x;   // 4096 exact
    int b = idx >> 9, d = idx & 511;
    float s = 0.f, m = -3.0e38f;
    for (int c = 0; c < 64; c++) {
        s += psum[((size_t)b * 64 + c) * 512 + d];
        m = fmaxf(m, pmax[((size_t)b * 64 + c) * 512 + d]);
    }
    pooled[idx] = 0.5f * (s * (1.f / 1024.f) + m);
}

// ---------------- small FC ----------------
template <int ACT>
__global__ void k_fc(const float* __restrict__ in, const float* __restrict__ W,
                     const float* __restrict__ bias, float* __restrict__ out,
                     int BN, int N, int K) {
    int idx = blockIdx.x * 64 + threadIdx.x;
    if (idx >= BN) return;
    int b = idx / N, n = idx % N;
    const float* a = in + (size_t)b * K;
    const float* w = W + (size_t)n * K;
    float acc = 0.f;
    for (int k = 0; k < K; k += 4) {
        float4 av = *(const float4*)(a + k);
        float4 wv = *(const float4*)(w + k);
        acc += av.x * wv.x + av.y * wv.y + av.z * wv.z + av.w * wv.w;
    }
    float v = acc + bias[n];
    if (ACT == 1) v = geluf(v);
    out[idx] = v;
}

extern "C" void kernel_launch(void* const* d_in, const int* in_sizes, int n_in,
                              void* d_out, int out_size, void* d_ws, size_t ws_size,
                              hipStream_t stream) {
    (void)in_sizes; (void)n_in; (void)out_size; (void)ws_size;
    const int*   tok        = (const int*)  d_in[0];
    const float* mask       = (const float*)d_in[1];
    const float* emb        = (const float*)d_in[2];
    const float* pos        = (const float*)d_in[3];
    const float* inp_w      = (const float*)d_in[4];
    const float* inp_b      = (const float*)d_in[5];
    const float* ln_g       = (const float*)d_in[6];
    const float* ln_b       = (const float*)d_in[7];
    const float* in_proj_w  = (const float*)d_in[8];
    const float* conv_w     = (const float*)d_in[9];
    const float* conv_b     = (const float*)d_in[10];
    const float* dt_bias    = (const float*)d_in[11];
    const float* A_log      = (const float*)d_in[12];
    const float* Dparam     = (const float*)d_in[13];
    const float* norm_w     = (const float*)d_in[14];
    const float* out_proj_w = (const float*)d_in[15];
    const float* pooler_w   = (const float*)d_in[16];
    const float* pooler_b   = (const float*)d_in[17];
    const float* cls_w1     = (const float*)d_in[18];
    const float* cls_b1     = (const float*)d_in[19];
    const float* cls_w2     = (const float*)d_in[20];
    const float* cls_b2     = (const float*)d_in[21];
    float* out = (float*)d_out;

    float* ws     = (float*)d_ws;
    float* x      = ws;                                // 8192*512 (prologue only)
    float* dt_raw = x + (size_t)8192 * 512;            // 8192*16
    float* elbuf  = dt_raw + (size_t)8192 * 16;        // 131072
    float* psum   = elbuf + 131072;                    // 262144
    float* pmax   = psum + 262144;                     // 262144
    float* pooled = pmax + 262144;                     // 4096
    float* pbuf   = pooled + 4096;                     // 4096
    float* cbuf   = pbuf + 4096;                       // 2048
    u16* x_bf    = (u16*)(cbuf + 2048);                // 8192*512 (bf16 residual)
    u16* z_bf    = x_bf + (size_t)8192 * 512;          // 8192*1024
    u16* xbc_in  = z_bf + (size_t)8192 * 1024;         // 8192*1280 (conv input bf16)
    u16* y_bf    = xbc_in + (size_t)8192 * 1280;       // 8192*1024 (gate out)
    u16* xhbf    = y_bf + (size_t)8192 * 1024;         // 8192*1024
    u16* bcbf    = xhbf + (size_t)8192 * 1024;         // 8192*256
    u16* y16     = bcbf + (size_t)8192 * 256;          // 8192*1024 (SSM out, bf16)
    u16* wip_bf  = y16 + (size_t)8192 * 1024;          // 4*2432*512
    u16* wop_bf  = wip_bf + (size_t)4 * 2432 * 512;    // 4*512*1024
    u16* winp_bf = wop_bf + (size_t)4 * 512 * 1024;    // 512*512
    // overlays in dead windows:
    u16* xe_bf   = (u16*)y16;                          // prologue only (y16 dead)
    u16* scb16   = xbc_in;                             // over xbc_in (dead between
                                                       // k_ssd and next in_proj)

    // merged weight casts (single dispatch)
    k_casts<<<7168, 256, 0, stream>>>(in_proj_w, out_proj_w, inp_w,
                                      wip_bf, wop_bf, winp_bf);

    // embedding + positional (bf16)
    k_embed<<<4096, 256, 0, stream>>>(tok, emb, pos, xe_bf);
    // x = embed @ inp_w^T + inp_b  (fp32, prologue only)
    k_gemm_mfma<1><<<256, 512, 0, stream>>>(xe_bf, winp_bf, inp_b, x, nullptr,
                                            nullptr, 8192, 512, 512, 4);
    // LN -> bf16 residual stream x_bf
    k_layernorm<<<8192, 128, 0, stream>>>(x, ln_g, ln_b, mask, x_bf);

    for (int i = 0; i < 4; i++) {
        // split in_proj: z_bf | xbc_in (bf16) | dt_raw (f32); 256x128 tile
        k_gemm_in<<<608, 512, 0, stream>>>(x_bf, wip_bf + (size_t)i * 2432 * 512,
                                           z_bf, xbc_in, dt_raw);
        k_conv<<<8192, 320, 0, stream>>>(xbc_in, conv_w + (size_t)i * 1280 * 4,
                                         conv_b + (size_t)i * 1280, xhbf, bcbf);
        k_ssd<<<1024, 256, 0, stream>>>(xhbf, bcbf, dt_raw, dt_bias + i * 16,
                                        A_log + i * 16, elbuf, y16, scb16);
        k_states<<<128, 512, 0, stream>>>(scb16, elbuf);
        k_inter<<<1024, 256, 0, stream>>>(xhbf, bcbf, elbuf, scb16,
                                          Dparam + (size_t)i * 16, y16);
        k_gate<<<8192, 256, 0, stream>>>(y16, z_bf, norm_w + (size_t)i * 1024, y_bf);
        // x_bf = bf16((x_bf + y @ out_proj_w[i]^T) * mask)   (bf16 residual RMW)
        k_gemm_mfma<2><<<256, 512, 0, stream>>>(y_bf, wop_bf + (size_t)i * 512 * 1024,
                                                nullptr, nullptr, x_bf, mask,
                                                8192, 512, 1024, 4);
    }

    k_pool1<<<512, 256, 0, stream>>>(x_bf, psum, pmax);
    k_pool2<<<16, 256, 0, stream>>>(psum, pmax, pooled);
    k_fc<1><<<64, 64, 0, stream>>>(pooled, pooler_w, pooler_b, pbuf, 8 * 512, 512, 512);
    k_fc<1><<<32, 64, 0, stream>>>(pbuf, cls_w1, cls_b1, cbuf, 8 * 256, 256, 512);
    k_fc<0><<<1, 64, 0, stream>>>(cbuf, cls_w2, cls_b2, out, 8 * 2, 2, 256);
}

// Round 20
// 813.787 us; speedup vs baseline: 1.0094x; 1.0094x over previous
//
#include <hip/hip_runtime.h>

#define EPS 1e-5f
typedef unsigned short u16;
typedef short s16x8 __attribute__((ext_vector_type(8)));
typedef float f32x4 __attribute__((ext_vector_type(4)));

__device__ __forceinline__ float siluf(float x) { return x / (1.0f + __expf(-x)); }
__device__ __forceinline__ float geluf(float x) {
    float u = 0.7978845608028654f * (x + 0.044715f * x * x * x);
    return 0.5f * x * (1.0f + tanhf(u));
}
__device__ __forceinline__ u16 f2bf(float f) {
    unsigned u = __float_as_uint(f);
    return (u16)((u + 0x7fffu + ((u >> 16) & 1u)) >> 16);
}
__device__ __forceinline__ float bf2f(u16 v) {
    return __uint_as_float(((unsigned)v) << 16);
}
struct u16x4 { u16 x, y, z, w; };
__device__ __forceinline__ u16x4 f2bf4(float4 v) {
    u16x4 r; r.x = f2bf(v.x); r.y = f2bf(v.y); r.z = f2bf(v.z); r.w = f2bf(v.w);
    return r;
}

#define GLOAD_LDS16(gp, lp) __builtin_amdgcn_global_load_lds( \
    (const __attribute__((address_space(1))) void*)(gp),      \
    (__attribute__((address_space(3))) void*)(lp), 16, 0, 0)

// ---------------- merged weight casts (one dispatch) ----------------
__global__ void k_casts(const float* __restrict__ ip, const float* __restrict__ op,
                        const float* __restrict__ inp, u16* __restrict__ wip,
                        u16* __restrict__ wop, u16* __restrict__ winp) {
    int idx = blockIdx.x * 256 + threadIdx.x;   // 1835008 total
    if (idx < 1245184) {                        // in_proj, zero-pad rows >= 2320
        int e4 = idx * 4;
        int layer = e4 / 1245184;
        int rem   = e4 - layer * 1245184;
        int row   = rem >> 9;
        int k     = rem & 511;
        float4 v = make_float4(0.f, 0.f, 0.f, 0.f);
        if (row < 2320)
            v = *(const float4*)(ip + (size_t)layer * 1187840 + (size_t)row * 512 + k);
        *(u16x4*)(wip + e4) = f2bf4(v);
    } else if (idx < 1245184 + 524288) {        // out_proj
        int j = idx - 1245184;
        float4 v = *(const float4*)(op + (size_t)j * 4);
        *(u16x4*)(wop + (size_t)j * 4) = f2bf4(v);
    } else if (idx < 1245184 + 524288 + 65536) {  // inp
        int j = idx - 1245184 - 524288;
        float4 v = *(const float4*)(inp + (size_t)j * 4);
        *(u16x4*)(winp + (size_t)j * 4) = f2bf4(v);
    }
}

// ---------------- embedding + positional -> bf16 ----------------
__global__ void k_embed(const int* __restrict__ tok, const float* __restrict__ emb,
                        const float* __restrict__ pos, u16* __restrict__ out) {
    int idx = blockIdx.x * 256 + threadIdx.x;   // over 8192*512/4 = 1048576
    int d4 = idx & 127;
    int bl = idx >> 7;
    int l  = bl & 1023;
    float4 e = *(const float4*)(emb + tok[bl] * 512 + d4 * 4);
    float4 p = *(const float4*)(pos + l * 512 + d4 * 4);
    float4 v = make_float4(e.x + p.x, e.y + p.y, e.z + p.z, e.w + p.w);
    *(u16x4*)(out + (size_t)idx * 4) = f2bf4(v);
}

// ===== in_proj GEMM: 256x128 tile, 512 thr, wave-tile 64x64, 3-buf depth-2 ====
#define STAGE_I(buf, k0) do {                                                   \
    _Pragma("unroll")                                                           \
    for (int s_ = 0; s_ < 2; s_++) {                                            \
        int g_ = w * 2 + s_;                                                    \
        GLOAD_LDS16(A + (size_t)(m0 + g_ * 16 + lr) * 512 + (k0) + lk,          \
                    smem + (buf) * 8192 + g_ * 512);                            \
    }                                                                           \
    GLOAD_LDS16(B + (size_t)(n0 + w * 16 + lr) * 512 + (k0) + lk,               \
                smem + 24576 + (buf) * 4096 + w * 512);                         \
    } while (0)

#define COMPUTE_I(buf) do {                                                     \
    s16x8 af_[4], bf_[4];                                                       \
    _Pragma("unroll")                                                           \
    for (int i_ = 0; i_ < 4; i_++) {                                            \
        af_[i_] = *(const s16x8*)&smem[(buf) * 8192 + (wr * 4 + i_) * 512 + l * 8]; \
        bf_[i_] = *(const s16x8*)&smem[24576 + (buf) * 4096 + (wc * 4 + i_) * 512 + l * 8]; \
    }                                                                           \
    _Pragma("unroll")                                                           \
    for (int i_ = 0; i_ < 4; i_++)                                              \
        _Pragma("unroll")                                                       \
        for (int j_ = 0; j_ < 4; j_++)                                          \
            acc[i_][j_] = __builtin_amdgcn_mfma_f32_16x16x32_bf16(              \
                af_[i_], bf_[j_], acc[i_][j_], 0, 0, 0);                        \
    } while (0)

__global__ __launch_bounds__(512, 4) void k_gemm_in(
    const u16* __restrict__ A, const u16* __restrict__ B,
    u16* __restrict__ zbf, u16* __restrict__ xbcbf, float* __restrict__ dtw) {
    __shared__ __align__(16) u16 smem[36864];   // 3x8192 A | 3x4096 B; ep 256x136
    const int t = threadIdx.x;
    const int w = t >> 6, l = t & 63;
    const int wr = w >> 1, wc = w & 1;          // 4x2 wave grid, wave-tile 64x64
    const int lr = l & 15, lk = (l >> 4) * 8;
    const int wgid = (blockIdx.x & 7) * 76 + (blockIdx.x >> 3);  // 608 = 8*76
    const int m0 = (wgid / 19) * 256;
    const int nt = wgid % 19;
    const int n0 = nt * 128;

    f32x4 acc[4][4] = {};

    STAGE_I(0, 0);
    STAGE_I(1, 32);
    for (int ki = 0; ki < 14; ki++) {           // nk = 16
        asm volatile("s_waitcnt vmcnt(3)" ::: "memory");
        __builtin_amdgcn_s_barrier();
        STAGE_I((ki + 2) % 3, (ki + 2) * 32);
        COMPUTE_I(ki % 3);
    }
    asm volatile("s_waitcnt vmcnt(3)" ::: "memory");
    __builtin_amdgcn_s_barrier();
    COMPUTE_I(14 % 3);
    asm volatile("s_waitcnt vmcnt(0)" ::: "memory");
    __builtin_amdgcn_s_barrier();
    COMPUTE_I(15 % 3);
    __syncthreads();

    if (nt < 18) {
        // repack to LDS (bf16), then coalesced u16x8 stores
#pragma unroll
        for (int i = 0; i < 4; i++)
#pragma unroll
            for (int j = 0; j < 4; j++)
#pragma unroll
                for (int r2 = 0; r2 < 4; r2++) {
                    int erow = wr * 64 + i * 16 + (l >> 4) * 4 + r2;
                    int ecol = wc * 64 + j * 16 + (l & 15);
                    smem[erow * 136 + ecol] = f2bf(acc[i][j][r2]);
                }
        __syncthreads();
        if (nt < 8) {
#pragma unroll
            for (int it = 0; it < 8; it++) {
                int v = it * 512 + t;
                int row = v >> 4, col = (v & 15) * 8;
                *(s16x8*)&zbf[(size_t)(m0 + row) * 1024 + n0 + col] =
                    *(const s16x8*)&smem[row * 136 + col];
            }
        } else {
            int nb = n0 - 1024;
#pragma unroll
            for (int it = 0; it < 8; it++) {
                int v = it * 512 + t;
                int row = v >> 4, col = (v & 15) * 8;
                *(s16x8*)&xbcbf[(size_t)(m0 + row) * 1280 + nb + col] =
                    *(const s16x8*)&smem[row * 136 + col];
            }
        }
    } else {
        // dt tile (cols 2304..2319 live, rest zero-pad)
#pragma unroll
        for (int i = 0; i < 4; i++) {
            int mb = m0 + wr * 64 + i * 16 + (l >> 4) * 4;
#pragma unroll
            for (int j = 0; j < 4; j++) {
                int n = n0 + wc * 64 + j * 16 + (l & 15);
#pragma unroll
                for (int r2 = 0; r2 < 4; r2++) {
                    if (n < 2320)
                        dtw[(size_t)(mb + r2) * 16 + (n - 2304)] = acc[i][j][r2];
                }
            }
        }
    }
}

// --- generic MFMA GEMM NT: 512 thr, wave-tile 64x32, 3-buf depth-2 -----------
// MODE 1: C = acc + bias[n] (f32)
// MODE 2: Cbf = bf16((bf2f(Cbf) + acc) * mask[m])   (bf16 residual RMW)
#define STAGE(buf, k0) do {                                                     \
    GLOAD_LDS16(A + (size_t)(m0 + w * 16 + lr) * K + (k0) + lk,                 \
                &Asm[buf][w * 512]);                                            \
    GLOAD_LDS16(B + (size_t)(n0 + w * 16 + lr) * K + (k0) + lk,                 \
                &Bsm[buf][w * 512]);                                            \
    } while (0)

#define COMPUTE(buf) do {                                                       \
    s16x8 af_[4], bf_[2];                                                       \
    _Pragma("unroll")                                                           \
    for (int i_ = 0; i_ < 4; i_++)                                              \
        af_[i_] = *(const s16x8*)&Asm[buf][(wr * 4 + i_) * 512 + l * 8];        \
    _Pragma("unroll")                                                           \
    for (int j_ = 0; j_ < 2; j_++)                                              \
        bf_[j_] = *(const s16x8*)&Bsm[buf][(wc * 2 + j_) * 512 + l * 8];        \
    _Pragma("unroll")                                                           \
    for (int i_ = 0; i_ < 4; i_++)                                              \
        _Pragma("unroll")                                                       \
        for (int j_ = 0; j_ < 2; j_++)                                          \
            acc[i_][j_] = __builtin_amdgcn_mfma_f32_16x16x32_bf16(              \
                af_[i_], bf_[j_], acc[i_][j_], 0, 0, 0);                        \
    } while (0)

template <int MODE>
__global__ __launch_bounds__(512) void k_gemm_mfma(
    const u16* __restrict__ A, const u16* __restrict__ B,
    const float* __restrict__ bias, float* __restrict__ C,
    u16* __restrict__ Cbf, const float* __restrict__ mask,
    int M, int N, int K, int gx) {
    __shared__ u16 Asm[3][4096];
    __shared__ u16 Bsm[3][4096];
    const int t = threadIdx.x;
    const int w = t >> 6, l = t & 63;
    const int wr = w >> 2, wc = w & 3;          // 2x4 wave grid, wave-tile 64x32
    const int lr = l & 15, lk = (l >> 4) * 8;
    const int nwg = gridDim.x;
    const int q = nwg >> 3, r = nwg & 7;
    const int x8 = blockIdx.x & 7, d8 = blockIdx.x >> 3;
    const int wgid = (x8 < r) ? x8 * (q + 1) + d8 : r * (q + 1) + (x8 - r) * q + d8;
    const int m0 = (wgid / gx) * 128;
    const int n0 = (wgid % gx) * 128;

    f32x4 acc[4][2] = {};

    const int nk = K >> 5;
    STAGE(0, 0);
    STAGE(1, 32);
    for (int ki = 0; ki < nk - 2; ki++) {
        asm volatile("s_waitcnt vmcnt(2)" ::: "memory");
        __builtin_amdgcn_s_barrier();
        STAGE((ki + 2) % 3, (ki + 2) * 32);
        COMPUTE(ki % 3);
    }
    asm volatile("s_waitcnt vmcnt(2)" ::: "memory");
    __builtin_amdgcn_s_barrier();
    COMPUTE((nk - 2) % 3);
    asm volatile("s_waitcnt vmcnt(0)" ::: "memory");
    __builtin_amdgcn_s_barrier();
    COMPUTE((nk - 1) % 3);

#pragma unroll
    for (int i = 0; i < 4; i++) {
        int mb = m0 + wr * 64 + i * 16 + (l >> 4) * 4;
#pragma unroll
        for (int j = 0; j < 2; j++) {
            int n = n0 + wc * 32 + j * 16 + (l & 15);
#pragma unroll
            for (int r2 = 0; r2 < 4; r2++) {
                int m = mb + r2;
                float v = acc[i][j][r2];
                if (n < N) {
                    size_t o = (size_t)m * N + n;
                    if (MODE == 1) {
                        C[o] = v + bias[n];
                    } else {
                        float v2 = (bf2f(Cbf[o]) + v) * mask[m];
                        Cbf[o] = f2bf(v2);
                    }
                }
            }
        }
    }
}

// ---------------- LayerNorm + mask -> bf16 only ----------------
__global__ __launch_bounds__(128) void k_layernorm(
    const float* __restrict__ x, const float* __restrict__ g,
    const float* __restrict__ b, const float* __restrict__ mask,
    u16* __restrict__ xbf) {
    __shared__ float2 sbuf[2];
    int bl = blockIdx.x;
    int t  = threadIdx.x;
    float4 v = *(const float4*)(x + (size_t)bl * 512 + t * 4);
    float s = v.x + v.y + v.z + v.w;
    float q = v.x * v.x + v.y * v.y + v.z * v.z + v.w * v.w;
    for (int off = 32; off; off >>= 1) {
        s += __shfl_xor(s, off, 64);
        q += __shfl_xor(q, off, 64);
    }
    int wid = t >> 6, lane = t & 63;
    if (lane == 0) sbuf[wid] = make_float2(s, q);
    __syncthreads();
    float ts = sbuf[0].x + sbuf[1].x;
    float tq = sbuf[0].y + sbuf[1].y;
    float mu  = ts * (1.f / 512.f);
    float var = tq * (1.f / 512.f) - mu * mu;
    float inv = 1.0f / sqrtf(var + EPS);
    float mk  = mask[bl];
    float4 gg = *(const float4*)(g + t * 4);
    float4 bb = *(const float4*)(b + t * 4);
    float4 o;
    o.x = ((v.x - mu) * inv * gg.x + bb.x) * mk;
    o.y = ((v.y - mu) * inv * gg.y + bb.y) * mk;
    o.z = ((v.z - mu) * inv * gg.z + bb.z) * mk;
    o.w = ((v.w - mu) * inv * gg.w + bb.w) * mk;
    *(u16x4*)(xbf + (size_t)bl * 512 + t * 4) = f2bf4(o);
}

// --- causal depthwise conv (k=4, bf16 in) + bias + SiLU -> bf16 (xh | B/C) ---
__global__ __launch_bounds__(320) void k_conv(
    const u16* __restrict__ xbc_in, const float* __restrict__ cw,
    const float* __restrict__ cb, u16* __restrict__ xhbf,
    u16* __restrict__ bcbf) {
    int bid = blockIdx.x;
    int bl = (bid & 7) * 1024 + (bid >> 3);    // 8192 rows, bijective
    int l  = bl & 1023;
    int c  = threadIdx.x * 4;
    float4 w0 = *(const float4*)(cw + (c + 0) * 4);
    float4 w1 = *(const float4*)(cw + (c + 1) * 4);
    float4 w2 = *(const float4*)(cw + (c + 2) * 4);
    float4 w3 = *(const float4*)(cw + (c + 3) * 4);
    float4 a  = *(const float4*)(cb + c);
#pragma unroll
    for (int k = 0; k < 4; k++) {
        if (l + k - 3 >= 0) {
            u16x4 v = *(const u16x4*)(xbc_in + (size_t)(bl + k - 3) * 1280 + c);
            const float* wk0 = (const float*)&w0;
            const float* wk1 = (const float*)&w1;
            const float* wk2 = (const float*)&w2;
            const float* wk3 = (const float*)&w3;
            a.x = fmaf(bf2f(v.x), wk0[k], a.x);
            a.y = fmaf(bf2f(v.y), wk1[k], a.y);
            a.z = fmaf(bf2f(v.z), wk2[k], a.z);
            a.w = fmaf(bf2f(v.w), wk3[k], a.w);
        }
    }
    float4 o = make_float4(siluf(a.x), siluf(a.y), siluf(a.z), siluf(a.w));
    if (c < 1024)
        *(u16x4*)(xhbf + (size_t)bl * 1024 + c) = f2bf4(o);
    else
        *(u16x4*)(bcbf + (size_t)bl * 256 + (c - 1024)) = f2bf4(o);
}

// ============ fused SSD intra (r12 layout; vectorized UT/BTw global reads) ====
#define SSD_STAGE(dst, k0) do {                                                 \
    _Pragma("unroll")                                                           \
    for (int s_ = 0; s_ < 2; s_++) {                                            \
        int g_ = w * 2 + s_;                                                    \
        GLOAD_LDS16(bcbf + (row0 + g_ * 16 + lr) * 256 + 128 + (k0) + lk8,      \
                    (dst) + g_ * 512);                                          \
        GLOAD_LDS16(bcbf + (row0 + g_ * 16 + lr) * 256 + (k0) + lk8,            \
                    (dst) + 4096 + g_ * 512);                                   \
    } } while (0)

__global__ __launch_bounds__(256) void k_ssd(
    const u16* __restrict__ xhbf, const u16* __restrict__ bcbf,
    const float* __restrict__ dt_raw, const float* __restrict__ dtbias,
    const float* __restrict__ alog, float* __restrict__ elbuf,
    u16* __restrict__ y16, u16* __restrict__ scb16) {
    int bid = blockIdx.x;
    int bhc = (bid & 7) * 128 + (bid >> 3);   // bijective; batch b stays on one XCD
    int c = bhc & 7, h = (bhc >> 3) & 15, b = bhc >> 7;
    const size_t row0 = (size_t)b * 1024 + c * 128;
    const int t = threadIdx.x, w = t >> 6, l = t & 63;
    const int wr = w >> 1, wc = w & 1;
    const int lr = l & 15, lk8 = (l >> 4) * 8;

    __shared__ float cl[128], dtl[128], wv[128];
    __shared__ float csh;
    __shared__ __align__(16) u16 shA[8704];
    __shared__ __align__(16) u16 shB[17408];

    // early scalar loads, then issue phase-1 stages (DMA hides under cumsum)
    float dtb_h = dtbias[h];
    float A = -__expf(alog[h]);
    float raw = 0.f;
    if (t < 128) raw = dt_raw[(row0 + t) * 16 + h] + dtb_h;
    SSD_STAGE(shA, 0);
    SSD_STAGE(shB, 32);

    float v = 0.f;
    if (t < 128) {
        float s = (raw > 20.f) ? raw : log1pf(__expf(raw));
        dtl[t] = s;
        v = s * A;
        int lane = t & 63;
#pragma unroll
        for (int off = 1; off < 64; off <<= 1) {
            float o = __shfl_up(v, off, 64);
            if (lane >= off) v += o;
        }
        if (t == 63) csh = v;
    }
    __syncthreads();
    if (t >= 64 && t < 128) v += csh;
    if (t < 128) {
        cl[t] = v;
        elbuf[(size_t)bhc * 128 + t] = __expf(v);
    }
    __syncthreads();
    if (t < 128) wv[t] = __expf(cl[127] - cl[t]);

    // ---- phase 1: S = C.B^T (2-buf ping-pong, counted vmcnt)
    f32x4 acc[4][4] = {};
    for (int ks = 0; ks < 4; ks++) {
        u16* cur = (ks & 1) ? shB : shA;
        if (ks < 3) asm volatile("s_waitcnt vmcnt(4)" ::: "memory");
        else        asm volatile("s_waitcnt vmcnt(0)" ::: "memory");
        __builtin_amdgcn_s_barrier();
        s16x8 af[4], bfr[4];
#pragma unroll
        for (int i = 0; i < 4; i++) {
            af[i]  = *(const s16x8*)&cur[(wr * 4 + i) * 512 + l * 8];
            bfr[i] = *(const s16x8*)&cur[4096 + (wc * 4 + i) * 512 + l * 8];
        }
#pragma unroll
        for (int i = 0; i < 4; i++)
#pragma unroll
            for (int j = 0; j < 4; j++)
                acc[i][j] = __builtin_amdgcn_mfma_f32_16x16x32_bf16(af[i], bfr[j], acc[i][j], 0, 0, 0);
        __builtin_amdgcn_s_barrier();
        if (ks + 2 < 4) SSD_STAGE(cur, (ks + 2) * 32);
    }

    // ---- UT build: UT[p][j] = dt[j]*x[j][p]; vectorized u16x8 global reads
    {
        int j = t >> 1;                        // 0..127
        int ph = (t & 1) * 32;                 // p half
        float dj = dtl[j];
        const u16* src = xhbf + (row0 + j) * 1024 + h * 64 + ph;
#pragma unroll
        for (int vq = 0; vq < 4; vq++) {
            s16x8 vec = *(const s16x8*)(src + vq * 8);
            int p0 = ph + vq * 8;
#pragma unroll
            for (int i = 0; i < 8; i++)
                shA[(p0 + i) * 136 + j] = f2bf(dj * bf2f((u16)vec[i]));
        }
    }
    __syncthreads();

    // ---- phase 2: y = P.U  (P in 64-col halves)
    f32x4 acc2[4][2] = {};
    for (int half = 0; half < 2; half++) {
        if (wc == half) {
#pragma unroll
            for (int i = 0; i < 4; i++) {
#pragma unroll
                for (int j = 0; j < 4; j++) {
                    int col = half * 64 + j * 16 + (l & 15);
#pragma unroll
                    for (int r = 0; r < 4; r++) {
                        int row = wr * 64 + i * 16 + (l >> 4) * 4 + r;
                        float e = __expf(fminf(cl[row] - cl[col], 0.f));
                        float pv = (col <= row) ? acc[i][j][r] * e : 0.f;
                        shB[row * 72 + j * 16 + (l & 15)] = f2bf(pv);
                    }
                }
            }
        }
        __syncthreads();
#pragma unroll
        for (int ks = 0; ks < 2; ks++) {
            int kof = ks * 32;
            s16x8 pa[4], ub[2];
#pragma unroll
            for (int i = 0; i < 4; i++)
                pa[i] = *(const s16x8*)&shB[(wr * 64 + i * 16 + lr) * 72 + kof + lk8];
#pragma unroll
            for (int jj = 0; jj < 2; jj++)
                ub[jj] = *(const s16x8*)&shA[(wc * 32 + jj * 16 + lr) * 136 + half * 64 + kof + lk8];
#pragma unroll
            for (int i = 0; i < 4; i++)
#pragma unroll
                for (int jj = 0; jj < 2; jj++)
                    acc2[i][jj] = __builtin_amdgcn_mfma_f32_16x16x32_bf16(pa[i], ub[jj], acc2[i][jj], 0, 0, 0);
        }
        __syncthreads();
    }

    // ---- y_intra store: f32 repack in shB, then vector u16x8 stores
    {
        float* fb = (float*)shB;   // 128 x 68 f32 = 34816 B = sizeof(shB)
#pragma unroll
        for (int i = 0; i < 4; i++)
#pragma unroll
            for (int jj = 0; jj < 2; jj++)
#pragma unroll
                for (int r = 0; r < 4; r++) {
                    int row = wr * 64 + i * 16 + (l >> 4) * 4 + r;
                    fb[row * 68 + wc * 32 + jj * 16 + (l & 15)] = acc2[i][jj][r];
                }
        __syncthreads();
#pragma unroll
        for (int it = 0; it < 4; it++) {
            int vv = it * 256 + t;            // 128*64/8 = 1024 vectors
            int row = vv >> 3, col = (vv & 7) * 8;
            float4 f0 = *(const float4*)&fb[row * 68 + col];
            float4 f1 = *(const float4*)&fb[row * 68 + col + 4];
            s16x8 ov;
            const float* p0 = (const float*)&f0;
            const float* p1 = (const float*)&f1;
#pragma unroll
            for (int j = 0; j < 4; j++) { ov[j] = (short)f2bf(p0[j]); ov[4 + j] = (short)f2bf(p1[j]); }
            *(s16x8*)&y16[(row0 + row) * 1024 + h * 64 + col] = ov;
        }
        __syncthreads();
    }

    // ---- BTw build: BTw[n][j] = wv[j]*B[j][n]; vectorized u16x8 global reads
    {
        int j = t >> 1;                        // 0..127
        int nh = (t & 1) * 64;                 // n half
        float wj = wv[j];
        const u16* src = bcbf + (row0 + j) * 256 + nh;
#pragma unroll
        for (int vq = 0; vq < 8; vq++) {
            s16x8 vec = *(const s16x8*)(src + vq * 8);
            int n0 = nh + vq * 8;
#pragma unroll
            for (int i = 0; i < 8; i++)
                shB[(n0 + i) * 136 + j] = f2bf(wj * bf2f((u16)vec[i]));
        }
    }
    __syncthreads();

    // ---- phase 3: Sc = UT.(BTw) -> bf16 [p][128]
    f32x4 acc3[4][2] = {};
#pragma unroll
    for (int ks = 0; ks < 4; ks++) {
        int kof = ks * 32;
        s16x8 ua[4], bb[2];
#pragma unroll
        for (int i = 0; i < 4; i++)
            ua[i] = *(const s16x8*)&shA[(i * 16 + lr) * 136 + kof + lk8];
#pragma unroll
        for (int jj = 0; jj < 2; jj++)
            bb[jj] = *(const s16x8*)&shB[(w * 32 + jj * 16 + lr) * 136 + kof + lk8];
#pragma unroll
        for (int i = 0; i < 4; i++)
#pragma unroll
            for (int jj = 0; jj < 2; jj++)
                acc3[i][jj] = __builtin_amdgcn_mfma_f32_16x16x32_bf16(ua[i], bb[jj], acc3[i][jj], 0, 0, 0);
    }
#pragma unroll
    for (int i = 0; i < 4; i++)
#pragma unroll
        for (int jj = 0; jj < 2; jj++) {
            int n = w * 32 + jj * 16 + (l & 15);
#pragma unroll
            for (int r = 0; r < 4; r++) {
                int p = i * 16 + (l >> 4) * 4 + r;
                scb16[(size_t)bhc * 8192 + (size_t)p * 128 + n] = f2bf(acc3[i][jj][r]);
            }
        }
}

// sequential chunk-state recurrence (bf16 in/out, f32 accumulate)
__global__ __launch_bounds__(512) void k_states(u16* __restrict__ scb16,
                                                const float* __restrict__ elbuf) {
    int bh = blockIdx.x;                  // b*16+h
    int t = threadIdx.x;
    float hreg[16];
#pragma unroll
    for (int j = 0; j < 16; j++) hreg[j] = 0.f;
    size_t o = (size_t)t * 16;
    for (int c = 0; c < 8; c++) {
        int bhc = bh * 8 + c;
        float Tc = elbuf[(size_t)bhc * 128 + 127];
        u16* p = scb16 + (size_t)bhc * 8192 + o;
        s16x8 v0 = *(s16x8*)(p);
        s16x8 v1 = *(s16x8*)(p + 8);
        s16x8 o0, o1;
#pragma unroll
        for (int j = 0; j < 8; j++) {
            o0[j] = (short)f2bf(hreg[j]);
            o1[j] = (short)f2bf(hreg[8 + j]);
        }
        *(s16x8*)(p)     = o0;
        *(s16x8*)(p + 8) = o1;
#pragma unroll
        for (int j = 0; j < 8; j++) {
            hreg[j]     = fmaf(Tc, hreg[j],     bf2f((u16)v0[j]));
            hreg[8 + j] = fmaf(Tc, hreg[8 + j], bf2f((u16)v1[j]));
        }
    }
}

// ============ inter-chunk: pipelined stages + vector RMW epilogue ============
#define INT_STAGE(bf_, k0_) do {                                                \
    _Pragma("unroll")                                                           \
    for (int s_ = 0; s_ < 2; s_++) {                                            \
        int g_ = w * 2 + s_;                                                    \
        GLOAD_LDS16(bcbf + (row0 + g_ * 16 + lr) * 256 + 128 + (k0_) + lk8,     \
                    &CStg[bf_][g_ * 512]);                                      \
    }                                                                           \
    GLOAD_LDS16(scb16 + (size_t)bhc * 8192 + (size_t)(w * 16 + lr) * 128 + (k0_) + lk8, \
                &HStg[bf_][w * 512]);                                           \
    } while (0)

__global__ __launch_bounds__(256) void k_inter(
    const u16* __restrict__ xhbf, const u16* __restrict__ bcbf,
    const float* __restrict__ elbuf, const u16* __restrict__ scb16,
    const float* __restrict__ Dp, u16* __restrict__ y16) {
    int bid = blockIdx.x;
    int bhc = (bid & 7) * 128 + (bid >> 3);
    int c = bhc & 7, h = (bhc >> 3) & 15, b = bhc >> 7;
    const size_t row0 = (size_t)b * 1024 + c * 128;
    const int t = threadIdx.x, w = t >> 6, l = t & 63;
    const int wr = w >> 1, wc = w & 1;
    const int lr = l & 15, lk8 = (l >> 4) * 8;
    __shared__ __align__(16) u16 CStg[2][4096];
    __shared__ __align__(16) u16 HStg[2][2048];
    __shared__ __align__(16) float FY[64 * 68];
    __shared__ float el[128];
    float Dv = Dp[h];
    float elv = (t < 128) ? elbuf[(size_t)bhc * 128 + t] : 0.f;

    INT_STAGE(0, 0);
    INT_STAGE(1, 32);
    if (t < 128) el[t] = elv;

    f32x4 acc[4][2] = {};
    for (int ks = 0; ks < 4; ks++) {
        int cur = ks & 1;
        if (ks < 3) asm volatile("s_waitcnt vmcnt(3)" ::: "memory");
        else        asm volatile("s_waitcnt vmcnt(0)" ::: "memory");
        __builtin_amdgcn_s_barrier();
        s16x8 ca[4], hb[2];
#pragma unroll
        for (int i = 0; i < 4; i++)
            ca[i] = *(const s16x8*)&CStg[cur][(wr * 4 + i) * 512 + l * 8];
#pragma unroll
        for (int jj = 0; jj < 2; jj++)
            hb[jj] = *(const s16x8*)&HStg[cur][(wc * 2 + jj) * 512 + l * 8];
#pragma unroll
        for (int i = 0; i < 4; i++)
#pragma unroll
            for (int jj = 0; jj < 2; jj++)
                acc[i][jj] = __builtin_amdgcn_mfma_f32_16x16x32_bf16(ca[i], hb[jj], acc[i][jj], 0, 0, 0);
        __builtin_amdgcn_s_barrier();
        if (ks + 2 < 4) INT_STAGE(cur, (ks + 2) * 32);
    }

    // epilogue: chunked f32 repack (rows ch*64..) -> vector RMW
    for (int ch = 0; ch < 2; ch++) {
        if (wr == ch) {
#pragma unroll
            for (int i = 0; i < 4; i++)
#pragma unroll
                for (int jj = 0; jj < 2; jj++)
#pragma unroll
                    for (int r = 0; r < 4; r++) {
                        int rrow = i * 16 + (l >> 4) * 4 + r;   // 0..63
                        FY[rrow * 68 + wc * 32 + jj * 16 + (l & 15)] =
                            el[ch * 64 + rrow] * acc[i][jj][r];
                    }
        }
        __syncthreads();
#pragma unroll
        for (int it = 0; it < 2; it++) {
            int vv = it * 256 + t;            // 64*64/8 = 512 vectors
            int row = vv >> 3, col = (vv & 7) * 8;
            float4 f0 = *(const float4*)&FY[row * 68 + col];
            float4 f1 = *(const float4*)&FY[row * 68 + col + 4];
            size_t yo = (row0 + ch * 64 + row) * 1024 + h * 64 + col;
            s16x8 yv = *(const s16x8*)&y16[yo];
            s16x8 xv = *(const s16x8*)&xhbf[yo];
            s16x8 ov;
            const float* p0 = (const float*)&f0;
            const float* p1 = (const float*)&f1;
#pragma unroll
            for (int j = 0; j < 4; j++) {
                ov[j]     = (short)f2bf(bf2f((u16)yv[j])     + p0[j] + Dv * bf2f((u16)xv[j]));
                ov[4 + j] = (short)f2bf(bf2f((u16)yv[4 + j]) + p1[j] + Dv * bf2f((u16)xv[4 + j]));
            }
            *(s16x8*)&y16[yo] = ov;
        }
        __syncthreads();
    }
}

// ---------------- gate: ybf = bf16(rmsnorm(y * silu(z)) * norm_w) ----------------
__global__ __launch_bounds__(256) void k_gate(
    const u16* __restrict__ y16, const u16* __restrict__ zbf,
    const float* __restrict__ nw, u16* __restrict__ ybf) {
    __shared__ float sbuf[4];
    int bl = blockIdx.x;
    int t  = threadIdx.x;
    u16x4 yv4 = *(const u16x4*)(y16 + (size_t)bl * 1024 + t * 4);
    u16x4 zv4 = *(const u16x4*)(zbf + (size_t)bl * 1024 + t * 4);
    float4 gv;
    gv.x = bf2f(yv4.x) * siluf(bf2f(zv4.x));
    gv.y = bf2f(yv4.y) * siluf(bf2f(zv4.y));
    gv.z = bf2f(yv4.z) * siluf(bf2f(zv4.z));
    gv.w = bf2f(yv4.w) * siluf(bf2f(zv4.w));
    float q = gv.x * gv.x + gv.y * gv.y + gv.z * gv.z + gv.w * gv.w;
    for (int off = 32; off; off >>= 1) q += __shfl_xor(q, off, 64);
    int wid = t >> 6, lane = t & 63;
    if (lane == 0) sbuf[wid] = q;
    __syncthreads();
    float tot = sbuf[0] + sbuf[1] + sbuf[2] + sbuf[3];
    float scale = 1.0f / sqrtf(tot * (1.f / 1024.f) + EPS);
    float4 nv = *(const float4*)(nw + t * 4);
    float4 o;
    o.x = gv.x * scale * nv.x;
    o.y = gv.y * scale * nv.y;
    o.z = gv.z * scale * nv.z;
    o.w = gv.w * scale * nv.w;
    *(u16x4*)(ybf + (size_t)bl * 1024 + t * 4) = f2bf4(o);
}

// ---------------- pool stage 1 (bf16 input) ----------------
__global__ __launch_bounds__(256) void k_pool1(const u16* __restrict__ xbf,
                                               float* __restrict__ psum,
                                               float* __restrict__ pmax) {
    int blk = blockIdx.x;          // b*64 + lc
    int b = blk >> 6, lc = blk & 63;
    int t = threadIdx.x;
    const u16* px = xbf + (size_t)b * 524288 + (size_t)lc * 16 * 512;
    float s0 = 0.f, s1 = 0.f, m0 = -3.0e38f, m1 = -3.0e38f;
#pragma unroll
    for (int r = 0; r < 16; r++) {
        float v0 = bf2f(px[r * 512 + t]);
        float v1 = bf2f(px[r * 512 + t + 256]);
        s0 += v0; s1 += v1;
        m0 = fmaxf(m0, v0); m1 = fmaxf(m1, v1);
    }
    psum[(size_t)blk * 512 + t]       = s0;
    psum[(size_t)blk * 512 + t + 256] = s1;
    pmax[(size_t)blk * 512 + t]       = m0;
    pmax[(size_t)blk * 512 + t + 256] = m1;
}

// ---------------- pool stage 2 ----------------
__global__ __launch_bounds__(256) void k_pool2(const float* __restrict__ psum,
                                               const float* __restrict__ pmax,
                                               float* __restrict__ pooled) {
    int idx = blockIdx.x * 256 + threadIdx.x;   // 4096 exact
    int b = idx >> 9, d = idx & 511;
    float s = 0.f, m = -3.0e38f;
    for (int c = 0; c < 64; c++) {
        s += psum[((size_t)b * 64 + c) * 512 + d];
        m = fmaxf(m, pmax[((size_t)b * 64 + c) * 512 + d]);
    }
    pooled[idx] = 0.5f * (s * (1.f / 1024.f) + m);
}

// ---------------- small FC ----------------
template <int ACT>
__global__ void k_fc(const float* __restrict__ in, const float* __restrict__ W,
                     const float* __restrict__ bias, float* __restrict__ out,
                     int BN, int N, int K) {
    int idx = blockIdx.x * 64 + threadIdx.x;
    if (idx >= BN) return;
    int b = idx / N, n = idx % N;
    const float* a = in + (size_t)b * K;
    const float* w = W + (size_t)n * K;
    float acc = 0.f;
    for (int k = 0; k < K; k += 4) {
        float4 av = *(const float4*)(a + k);
        float4 wv = *(const float4*)(w + k);
        acc += av.x * wv.x + av.y * wv.y + av.z * wv.z + av.w * wv.w;
    }
    float v = acc + bias[n];
    if (ACT == 1) v = geluf(v);
    out[idx] = v;
}

extern "C" void kernel_launch(void* const* d_in, const int* in_sizes, int n_in,
                              void* d_out, int out_size, void* d_ws, size_t ws_size,
                              hipStream_t stream) {
    (void)in_sizes; (void)n_in; (void)out_size; (void)ws_size;
    const int*   tok        = (const int*)  d_in[0];
    const float* mask       = (const float*)d_in[1];
    const float* emb        = (const float*)d_in[2];
    const float* pos        = (const float*)d_in[3];
    const float* inp_w      = (const float*)d_in[4];
    const float* inp_b      = (const float*)d_in[5];
    const float* ln_g       = (const float*)d_in[6];
    const float* ln_b       = (const float*)d_in[7];
    const float* in_proj_w  = (const float*)d_in[8];
    const float* conv_w     = (const float*)d_in[9];
    const float* conv_b     = (const float*)d_in[10];
    const float* dt_bias    = (const float*)d_in[11];
    const float* A_log      = (const float*)d_in[12];
    const float* Dparam     = (const float*)d_in[13];
    const float* norm_w     = (const float*)d_in[14];
    const float* out_proj_w = (const float*)d_in[15];
    const float* pooler_w   = (const float*)d_in[16];
    const float* pooler_b   = (const float*)d_in[17];
    const float* cls_w1     = (const float*)d_in[18];
    const float* cls_b1     = (const float*)d_in[19];
    const float* cls_w2     = (const float*)d_in[20];
    const float* cls_b2     = (const float*)d_in[21];
    float* out = (float*)d_out;

    float* ws     = (float*)d_ws;
    float* x      = ws;                                // 8192*512 (prologue only)
    float* dt_raw = x + (size_t)8192 * 512;            // 8192*16
    float* elbuf  = dt_raw + (size_t)8192 * 16;        // 131072
    float* psum   = elbuf + 131072;                    // 262144
    float* pmax   = psum + 262144;                     // 262144
    float* pooled = pmax + 262144;                     // 4096
    float* pbuf   = pooled + 4096;                     // 4096
    float* cbuf   = pbuf + 4096;                       // 2048
    u16* x_bf    = (u16*)(cbuf + 2048);                // 8192*512 (bf16 residual)
    u16* z_bf    = x_bf + (size_t)8192 * 512;          // 8192*1024
    u16* xbc_in  = z_bf + (size_t)8192 * 1024;         // 8192*1280 (conv input bf16)
    u16* y_bf    = xbc_in + (size_t)8192 * 1280;       // 8192*1024 (gate out)
    u16* xhbf    = y_bf + (size_t)8192 * 1024;         // 8192*1024
    u16* bcbf    = xhbf + (size_t)8192 * 1024;         // 8192*256
    u16* y16     = bcbf + (size_t)8192 * 256;          // 8192*1024 (SSM out, bf16)
    u16* wip_bf  = y16 + (size_t)8192 * 1024;          // 4*2432*512
    u16* wop_bf  = wip_bf + (size_t)4 * 2432 * 512;    // 4*512*1024
    u16* winp_bf = wop_bf + (size_t)4 * 512 * 1024;    // 512*512
    // overlays in dead windows:
    u16* xe_bf   = (u16*)y16;                          // prologue only (y16 dead)
    u16* scb16   = xbc_in;                             // over xbc_in (dead between
                                                       // k_ssd and next in_proj)

    // merged weight casts (single dispatch)
    k_casts<<<7168, 256, 0, stream>>>(in_proj_w, out_proj_w, inp_w,
                                      wip_bf, wop_bf, winp_bf);

    // embedding + positional (bf16)
    k_embed<<<4096, 256, 0, stream>>>(tok, emb, pos, xe_bf);
    // x = embed @ inp_w^T + inp_b  (fp32, prologue only)
    k_gemm_mfma<1><<<256, 512, 0, stream>>>(xe_bf, winp_bf, inp_b, x, nullptr,
                                            nullptr, 8192, 512, 512, 4);
    // LN -> bf16 residual stream x_bf
    k_layernorm<<<8192, 128, 0, stream>>>(x, ln_g, ln_b, mask, x_bf);

    for (int i = 0; i < 4; i++) {
        // split in_proj: z_bf | xbc_in (bf16) | dt_raw (f32); 256x128 tile
        k_gemm_in<<<608, 512, 0, stream>>>(x_bf, wip_bf + (size_t)i * 2432 * 512,
                                           z_bf, xbc_in, dt_raw);
        k_conv<<<8192, 320, 0, stream>>>(xbc_in, conv_w + (size_t)i * 1280 * 4,
                                         conv_b + (size_t)i * 1280, xhbf, bcbf);
        k_ssd<<<1024, 256, 0, stream>>>(xhbf, bcbf, dt_raw, dt_bias + i * 16,
                                        A_log + i * 16, elbuf, y16, scb16);
        k_states<<<128, 512, 0, stream>>>(scb16, elbuf);
        k_inter<<<1024, 256, 0, stream>>>(xhbf, bcbf, elbuf, scb16,
                                          Dparam + (size_t)i * 16, y16);
        k_gate<<<8192, 256, 0, stream>>>(y16, z_bf, norm_w + (size_t)i * 1024, y_bf);
        // x_bf = bf16((x_bf + y @ out_proj_w[i]^T) * mask)   (bf16 residual RMW)
        k_gemm_mfma<2><<<256, 512, 0, stream>>>(y_bf, wop_bf + (size_t)i * 512 * 1024,
                                                nullptr, nullptr, x_bf, mask,
                                                8192, 512, 1024, 4);
    }

    k_pool1<<<512, 256, 0, stream>>>(x_bf, psum, pmax);
    k_pool2<<<16, 256, 0, stream>>>(psum, pmax, pooled);
    k_fc<1><<<64, 64, 0, stream>>>(pooled, pooler_w, pooler_b, pbuf, 8 * 512, 512, 512);
    k_fc<1><<<32, 64, 0, stream>>>(pbuf, cls_w1, cls_b1, cbuf, 8 * 256, 256, 512);
    k_fc<0><<<1, 64, 0, stream>>>(cbuf, cls_w2, cls_b2, out, 8 * 2, 2, 256);
}

// Round 21
// 810.606 us; speedup vs baseline: 1.0134x; 1.0039x over previous
//
#include <hip/hip_runtime.h>

#define EPS 1e-5f
typedef unsigned short u16;
typedef short s16x8 __attribute__((ext_vector_type(8)));
typedef float f32x4 __attribute__((ext_vector_type(4)));

__device__ __forceinline__ float siluf(float x) { return x / (1.0f + __expf(-x)); }
__device__ __forceinline__ float geluf(float x) {
    float u = 0.7978845608028654f * (x + 0.044715f * x * x * x);
    return 0.5f * x * (1.0f + tanhf(u));
}
__device__ __forceinline__ u16 f2bf(float f) {
    unsigned u = __float_as_uint(f);
    return (u16)((u + 0x7fffu + ((u >> 16) & 1u)) >> 16);
}
__device__ __forceinline__ float bf2f(u16 v) {
    return __uint_as_float(((unsigned)v) << 16);
}
struct u16x4 { u16 x, y, z, w; };
__device__ __forceinline__ u16x4 f2bf4(float4 v) {
    u16x4 r; r.x = f2bf(v.x); r.y = f2bf(v.y); r.z = f2bf(v.z); r.w = f2bf(v.w);
    return r;
}

#define GLOAD_LDS16(gp, lp) __builtin_amdgcn_global_load_lds( \
    (const __attribute__((address_space(1))) void*)(gp),      \
    (__attribute__((address_space(3))) void*)(lp), 16, 0, 0)

// ---------------- merged weight casts (one dispatch) ----------------
__global__ void k_casts(const float* __restrict__ ip, const float* __restrict__ op,
                        const float* __restrict__ inp, u16* __restrict__ wip,
                        u16* __restrict__ wop, u16* __restrict__ winp) {
    int idx = blockIdx.x * 256 + threadIdx.x;   // 1835008 total
    if (idx < 1245184) {                        // in_proj, zero-pad rows >= 2320
        int e4 = idx * 4;
        int layer = e4 / 1245184;
        int rem   = e4 - layer * 1245184;
        int row   = rem >> 9;
        int k     = rem & 511;
        float4 v = make_float4(0.f, 0.f, 0.f, 0.f);
        if (row < 2320)
            v = *(const float4*)(ip + (size_t)layer * 1187840 + (size_t)row * 512 + k);
        *(u16x4*)(wip + e4) = f2bf4(v);
    } else if (idx < 1245184 + 524288) {        // out_proj
        int j = idx - 1245184;
        float4 v = *(const float4*)(op + (size_t)j * 4);
        *(u16x4*)(wop + (size_t)j * 4) = f2bf4(v);
    } else if (idx < 1245184 + 524288 + 65536) {  // inp
        int j = idx - 1245184 - 524288;
        float4 v = *(const float4*)(inp + (size_t)j * 4);
        *(u16x4*)(winp + (size_t)j * 4) = f2bf4(v);
    }
}

// ---------------- embedding + positional -> bf16 ----------------
__global__ void k_embed(const int* __restrict__ tok, const float* __restrict__ emb,
                        const float* __restrict__ pos, u16* __restrict__ out) {
    int idx = blockIdx.x * 256 + threadIdx.x;   // over 8192*512/4 = 1048576
    int d4 = idx & 127;
    int bl = idx >> 7;
    int l  = bl & 1023;
    float4 e = *(const float4*)(emb + tok[bl] * 512 + d4 * 4);
    float4 p = *(const float4*)(pos + l * 512 + d4 * 4);
    float4 v = make_float4(e.x + p.x, e.y + p.y, e.z + p.z, e.w + p.w);
    *(u16x4*)(out + (size_t)idx * 4) = f2bf4(v);
}

// ===== in_proj GEMM: 256x128 tile, 512 thr, wave-tile 64x64, 3-buf depth-2 ====
#define STAGE_I(buf, k0) do {                                                   \
    _Pragma("unroll")                                                           \
    for (int s_ = 0; s_ < 2; s_++) {                                            \
        int g_ = w * 2 + s_;                                                    \
        GLOAD_LDS16(A + (size_t)(m0 + g_ * 16 + lr) * 512 + (k0) + lk,          \
                    smem + (buf) * 8192 + g_ * 512);                            \
    }                                                                           \
    GLOAD_LDS16(B + (size_t)(n0 + w * 16 + lr) * 512 + (k0) + lk,               \
                smem + 24576 + (buf) * 4096 + w * 512);                         \
    } while (0)

#define COMPUTE_I(buf) do {                                                     \
    s16x8 af_[4], bf_[4];                                                       \
    _Pragma("unroll")                                                           \
    for (int i_ = 0; i_ < 4; i_++) {                                            \
        af_[i_] = *(const s16x8*)&smem[(buf) * 8192 + (wr * 4 + i_) * 512 + l * 8]; \
        bf_[i_] = *(const s16x8*)&smem[24576 + (buf) * 4096 + (wc * 4 + i_) * 512 + l * 8]; \
    }                                                                           \
    _Pragma("unroll")                                                           \
    for (int i_ = 0; i_ < 4; i_++)                                              \
        _Pragma("unroll")                                                       \
        for (int j_ = 0; j_ < 4; j_++)                                          \
            acc[i_][j_] = __builtin_amdgcn_mfma_f32_16x16x32_bf16(              \
                af_[i_], bf_[j_], acc[i_][j_], 0, 0, 0);                        \
    } while (0)

__global__ __launch_bounds__(512, 4) void k_gemm_in(
    const u16* __restrict__ A, const u16* __restrict__ B,
    u16* __restrict__ zbf, u16* __restrict__ xbcbf, float* __restrict__ dtw) {
    __shared__ __align__(16) u16 smem[36864];   // 3x8192 A | 3x4096 B; ep 256x136
    const int t = threadIdx.x;
    const int w = t >> 6, l = t & 63;
    const int wr = w >> 1, wc = w & 1;          // 4x2 wave grid, wave-tile 64x64
    const int lr = l & 15, lk = (l >> 4) * 8;
    const int wgid = (blockIdx.x & 7) * 76 + (blockIdx.x >> 3);  // 608 = 8*76
    const int m0 = (wgid / 19) * 256;
    const int nt = wgid % 19;
    const int n0 = nt * 128;

    f32x4 acc[4][4] = {};

    STAGE_I(0, 0);
    STAGE_I(1, 32);
    for (int ki = 0; ki < 14; ki++) {           // nk = 16
        asm volatile("s_waitcnt vmcnt(3)" ::: "memory");
        __builtin_amdgcn_s_barrier();
        STAGE_I((ki + 2) % 3, (ki + 2) * 32);
        COMPUTE_I(ki % 3);
    }
    asm volatile("s_waitcnt vmcnt(3)" ::: "memory");
    __builtin_amdgcn_s_barrier();
    COMPUTE_I(14 % 3);
    asm volatile("s_waitcnt vmcnt(0)" ::: "memory");
    __builtin_amdgcn_s_barrier();
    COMPUTE_I(15 % 3);
    __syncthreads();

    if (nt < 18) {
        // repack to LDS (bf16), then coalesced u16x8 stores
#pragma unroll
        for (int i = 0; i < 4; i++)
#pragma unroll
            for (int j = 0; j < 4; j++)
#pragma unroll
                for (int r2 = 0; r2 < 4; r2++) {
                    int erow = wr * 64 + i * 16 + (l >> 4) * 4 + r2;
                    int ecol = wc * 64 + j * 16 + (l & 15);
                    smem[erow * 136 + ecol] = f2bf(acc[i][j][r2]);
                }
        __syncthreads();
        if (nt < 8) {
#pragma unroll
            for (int it = 0; it < 8; it++) {
                int v = it * 512 + t;
                int row = v >> 4, col = (v & 15) * 8;
                *(s16x8*)&zbf[(size_t)(m0 + row) * 1024 + n0 + col] =
                    *(const s16x8*)&smem[row * 136 + col];
            }
        } else {
            int nb = n0 - 1024;
#pragma unroll
            for (int it = 0; it < 8; it++) {
                int v = it * 512 + t;
                int row = v >> 4, col = (v & 15) * 8;
                *(s16x8*)&xbcbf[(size_t)(m0 + row) * 1280 + nb + col] =
                    *(const s16x8*)&smem[row * 136 + col];
            }
        }
    } else {
        // dt tile (cols 2304..2319 live, rest zero-pad)
#pragma unroll
        for (int i = 0; i < 4; i++) {
            int mb = m0 + wr * 64 + i * 16 + (l >> 4) * 4;
#pragma unroll
            for (int j = 0; j < 4; j++) {
                int n = n0 + wc * 64 + j * 16 + (l & 15);
#pragma unroll
                for (int r2 = 0; r2 < 4; r2++) {
                    if (n < 2320)
                        dtw[(size_t)(mb + r2) * 16 + (n - 2304)] = acc[i][j][r2];
                }
            }
        }
    }
}

// --- generic MFMA GEMM NT: 512 thr, wave-tile 64x32, 3-buf depth-2 -----------
// MODE 1: C = acc + bias[n] (f32)
// MODE 2: Cbf = bf16((bf2f(Cbf) + acc) * mask[m])   (bf16 residual RMW)
#define STAGE(buf, k0) do {                                                     \
    GLOAD_LDS16(A + (size_t)(m0 + w * 16 + lr) * K + (k0) + lk,                 \
                &Asm[buf][w * 512]);                                            \
    GLOAD_LDS16(B + (size_t)(n0 + w * 16 + lr) * K + (k0) + lk,                 \
                &Bsm[buf][w * 512]);                                            \
    } while (0)

#define COMPUTE(buf) do {                                                       \
    s16x8 af_[4], bf_[2];                                                       \
    _Pragma("unroll")                                                           \
    for (int i_ = 0; i_ < 4; i_++)                                              \
        af_[i_] = *(const s16x8*)&Asm[buf][(wr * 4 + i_) * 512 + l * 8];        \
    _Pragma("unroll")                                                           \
    for (int j_ = 0; j_ < 2; j_++)                                              \
        bf_[j_] = *(const s16x8*)&Bsm[buf][(wc * 2 + j_) * 512 + l * 8];        \
    _Pragma("unroll")                                                           \
    for (int i_ = 0; i_ < 4; i_++)                                              \
        _Pragma("unroll")                                                       \
        for (int j_ = 0; j_ < 2; j_++)                                          \
            acc[i_][j_] = __builtin_amdgcn_mfma_f32_16x16x32_bf16(              \
                af_[i_], bf_[j_], acc[i_][j_], 0, 0, 0);                        \
    } while (0)

template <int MODE>
__global__ __launch_bounds__(512) void k_gemm_mfma(
    const u16* __restrict__ A, const u16* __restrict__ B,
    const float* __restrict__ bias, float* __restrict__ C,
    u16* __restrict__ Cbf, const float* __restrict__ mask,
    int M, int N, int K, int gx) {
    __shared__ u16 Asm[3][4096];
    __shared__ u16 Bsm[3][4096];
    const int t = threadIdx.x;
    const int w = t >> 6, l = t & 63;
    const int wr = w >> 2, wc = w & 3;          // 2x4 wave grid, wave-tile 64x32
    const int lr = l & 15, lk = (l >> 4) * 8;
    const int nwg = gridDim.x;
    const int q = nwg >> 3, r = nwg & 7;
    const int x8 = blockIdx.x & 7, d8 = blockIdx.x >> 3;
    const int wgid = (x8 < r) ? x8 * (q + 1) + d8 : r * (q + 1) + (x8 - r) * q + d8;
    const int m0 = (wgid / gx) * 128;
    const int n0 = (wgid % gx) * 128;

    f32x4 acc[4][2] = {};

    const int nk = K >> 5;
    STAGE(0, 0);
    STAGE(1, 32);
    for (int ki = 0; ki < nk - 2; ki++) {
        asm volatile("s_waitcnt vmcnt(2)" ::: "memory");
        __builtin_amdgcn_s_barrier();
        STAGE((ki + 2) % 3, (ki + 2) * 32);
        COMPUTE(ki % 3);
    }
    asm volatile("s_waitcnt vmcnt(2)" ::: "memory");
    __builtin_amdgcn_s_barrier();
    COMPUTE((nk - 2) % 3);
    asm volatile("s_waitcnt vmcnt(0)" ::: "memory");
    __builtin_amdgcn_s_barrier();
    COMPUTE((nk - 1) % 3);

#pragma unroll
    for (int i = 0; i < 4; i++) {
        int mb = m0 + wr * 64 + i * 16 + (l >> 4) * 4;
#pragma unroll
        for (int j = 0; j < 2; j++) {
            int n = n0 + wc * 32 + j * 16 + (l & 15);
#pragma unroll
            for (int r2 = 0; r2 < 4; r2++) {
                int m = mb + r2;
                float v = acc[i][j][r2];
                if (n < N) {
                    size_t o = (size_t)m * N + n;
                    if (MODE == 1) {
                        C[o] = v + bias[n];
                    } else {
                        float v2 = (bf2f(Cbf[o]) + v) * mask[m];
                        Cbf[o] = f2bf(v2);
                    }
                }
            }
        }
    }
}

// ---------------- LayerNorm + mask -> bf16 only ----------------
__global__ __launch_bounds__(128) void k_layernorm(
    const float* __restrict__ x, const float* __restrict__ g,
    const float* __restrict__ b, const float* __restrict__ mask,
    u16* __restrict__ xbf) {
    __shared__ float2 sbuf[2];
    int bl = blockIdx.x;
    int t  = threadIdx.x;
    float4 v = *(const float4*)(x + (size_t)bl * 512 + t * 4);
    float s = v.x + v.y + v.z + v.w;
    float q = v.x * v.x + v.y * v.y + v.z * v.z + v.w * v.w;
    for (int off = 32; off; off >>= 1) {
        s += __shfl_xor(s, off, 64);
        q += __shfl_xor(q, off, 64);
    }
    int wid = t >> 6, lane = t & 63;
    if (lane == 0) sbuf[wid] = make_float2(s, q);
    __syncthreads();
    float ts = sbuf[0].x + sbuf[1].x;
    float tq = sbuf[0].y + sbuf[1].y;
    float mu  = ts * (1.f / 512.f);
    float var = tq * (1.f / 512.f) - mu * mu;
    float inv = 1.0f / sqrtf(var + EPS);
    float mk  = mask[bl];
    float4 gg = *(const float4*)(g + t * 4);
    float4 bb = *(const float4*)(b + t * 4);
    float4 o;
    o.x = ((v.x - mu) * inv * gg.x + bb.x) * mk;
    o.y = ((v.y - mu) * inv * gg.y + bb.y) * mk;
    o.z = ((v.z - mu) * inv * gg.z + bb.z) * mk;
    o.w = ((v.w - mu) * inv * gg.w + bb.w) * mk;
    *(u16x4*)(xbf + (size_t)bl * 512 + t * 4) = f2bf4(o);
}

// --- causal depthwise conv (k=4, bf16 in) + bias + SiLU -> bf16 (xh | B/C) ---
__global__ __launch_bounds__(320) void k_conv(
    const u16* __restrict__ xbc_in, const float* __restrict__ cw,
    const float* __restrict__ cb, u16* __restrict__ xhbf,
    u16* __restrict__ bcbf) {
    int bid = blockIdx.x;
    int bl = (bid & 7) * 1024 + (bid >> 3);    // 8192 rows, bijective
    int l  = bl & 1023;
    int c  = threadIdx.x * 4;
    float4 w0 = *(const float4*)(cw + (c + 0) * 4);
    float4 w1 = *(const float4*)(cw + (c + 1) * 4);
    float4 w2 = *(const float4*)(cw + (c + 2) * 4);
    float4 w3 = *(const float4*)(cw + (c + 3) * 4);
    float4 a  = *(const float4*)(cb + c);
#pragma unroll
    for (int k = 0; k < 4; k++) {
        if (l + k - 3 >= 0) {
            u16x4 v = *(const u16x4*)(xbc_in + (size_t)(bl + k - 3) * 1280 + c);
            const float* wk0 = (const float*)&w0;
            const float* wk1 = (const float*)&w1;
            const float* wk2 = (const float*)&w2;
            const float* wk3 = (const float*)&w3;
            a.x = fmaf(bf2f(v.x), wk0[k], a.x);
            a.y = fmaf(bf2f(v.y), wk1[k], a.y);
            a.z = fmaf(bf2f(v.z), wk2[k], a.z);
            a.w = fmaf(bf2f(v.w), wk3[k], a.w);
        }
    }
    float4 o = make_float4(siluf(a.x), siluf(a.y), siluf(a.z), siluf(a.w));
    if (c < 1024)
        *(u16x4*)(xhbf + (size_t)bl * 1024 + c) = f2bf4(o);
    else
        *(u16x4*)(bcbf + (size_t)bl * 256 + (c - 1024)) = f2bf4(o);
}

// ============ fused SSD intra (r12 layout; vectorized UT/BTw global reads) ====
#define SSD_STAGE(dst, k0) do {                                                 \
    _Pragma("unroll")                                                           \
    for (int s_ = 0; s_ < 2; s_++) {                                            \
        int g_ = w * 2 + s_;                                                    \
        GLOAD_LDS16(bcbf + (row0 + g_ * 16 + lr) * 256 + 128 + (k0) + lk8,      \
                    (dst) + g_ * 512);                                          \
        GLOAD_LDS16(bcbf + (row0 + g_ * 16 + lr) * 256 + (k0) + lk8,            \
                    (dst) + 4096 + g_ * 512);                                   \
    } } while (0)

__global__ __launch_bounds__(256) void k_ssd(
    const u16* __restrict__ xhbf, const u16* __restrict__ bcbf,
    const float* __restrict__ dt_raw, const float* __restrict__ dtbias,
    const float* __restrict__ alog, float* __restrict__ elbuf,
    u16* __restrict__ y16, u16* __restrict__ scb16) {
    int bid = blockIdx.x;
    int bhc = (bid & 7) * 128 + (bid >> 3);   // bijective; batch b stays on one XCD
    int c = bhc & 7, h = (bhc >> 3) & 15, b = bhc >> 7;
    const size_t row0 = (size_t)b * 1024 + c * 128;
    const int t = threadIdx.x, w = t >> 6, l = t & 63;
    const int wr = w >> 1, wc = w & 1;
    const int lr = l & 15, lk8 = (l >> 4) * 8;

    __shared__ float cl[128], dtl[128], wv[128];
    __shared__ float csh;
    __shared__ __align__(16) u16 shA[8704];
    __shared__ __align__(16) u16 shB[17408];

    // early scalar loads, then issue phase-1 stages (DMA hides under cumsum)
    float dtb_h = dtbias[h];
    float A = -__expf(alog[h]);
    float raw = 0.f;
    if (t < 128) raw = dt_raw[(row0 + t) * 16 + h] + dtb_h;
    SSD_STAGE(shA, 0);
    SSD_STAGE(shB, 32);

    float v = 0.f;
    if (t < 128) {
        float s = (raw > 20.f) ? raw : log1pf(__expf(raw));
        dtl[t] = s;
        v = s * A;
        int lane = t & 63;
#pragma unroll
        for (int off = 1; off < 64; off <<= 1) {
            float o = __shfl_up(v, off, 64);
            if (lane >= off) v += o;
        }
        if (t == 63) csh = v;
    }
    __syncthreads();
    if (t >= 64 && t < 128) v += csh;
    if (t < 128) {
        cl[t] = v;
        elbuf[(size_t)bhc * 128 + t] = __expf(v);
    }
    __syncthreads();
    if (t < 128) wv[t] = __expf(cl[127] - cl[t]);

    // ---- phase 1: S = C.B^T (2-buf ping-pong, counted vmcnt)
    f32x4 acc[4][4] = {};
    for (int ks = 0; ks < 4; ks++) {
        u16* cur = (ks & 1) ? shB : shA;
        if (ks < 3) asm volatile("s_waitcnt vmcnt(4)" ::: "memory");
        else        asm volatile("s_waitcnt vmcnt(0)" ::: "memory");
        __builtin_amdgcn_s_barrier();
        s16x8 af[4], bfr[4];
#pragma unroll
        for (int i = 0; i < 4; i++) {
            af[i]  = *(const s16x8*)&cur[(wr * 4 + i) * 512 + l * 8];
            bfr[i] = *(const s16x8*)&cur[4096 + (wc * 4 + i) * 512 + l * 8];
        }
#pragma unroll
        for (int i = 0; i < 4; i++)
#pragma unroll
            for (int j = 0; j < 4; j++)
                acc[i][j] = __builtin_amdgcn_mfma_f32_16x16x32_bf16(af[i], bfr[j], acc[i][j], 0, 0, 0);
        __builtin_amdgcn_s_barrier();
        if (ks + 2 < 4) SSD_STAGE(cur, (ks + 2) * 32);
    }

    // ---- UT build: UT[p][j] = dt[j]*x[j][p]; vectorized u16x8 global reads
    {
        int j = t >> 1;                        // 0..127
        int ph = (t & 1) * 32;                 // p half
        float dj = dtl[j];
        const u16* src = xhbf + (row0 + j) * 1024 + h * 64 + ph;
#pragma unroll
        for (int vq = 0; vq < 4; vq++) {
            s16x8 vec = *(const s16x8*)(src + vq * 8);
            int p0 = ph + vq * 8;
#pragma unroll
            for (int i = 0; i < 8; i++)
                shA[(p0 + i) * 136 + j] = f2bf(dj * bf2f((u16)vec[i]));
        }
    }
    __syncthreads();

    // ---- phase 2: y = P.U  (P in 64-col halves)
    f32x4 acc2[4][2] = {};
    for (int half = 0; half < 2; half++) {
        if (wc == half) {
#pragma unroll
            for (int i = 0; i < 4; i++) {
#pragma unroll
                for (int j = 0; j < 4; j++) {
                    int col = half * 64 + j * 16 + (l & 15);
#pragma unroll
                    for (int r = 0; r < 4; r++) {
                        int row = wr * 64 + i * 16 + (l >> 4) * 4 + r;
                        float e = __expf(fminf(cl[row] - cl[col], 0.f));
                        float pv = (col <= row) ? acc[i][j][r] * e : 0.f;
                        shB[row * 72 + j * 16 + (l & 15)] = f2bf(pv);
                    }
                }
            }
        }
        __syncthreads();
#pragma unroll
        for (int ks = 0; ks < 2; ks++) {
            int kof = ks * 32;
            s16x8 pa[4], ub[2];
#pragma unroll
            for (int i = 0; i < 4; i++)
                pa[i] = *(const s16x8*)&shB[(wr * 64 + i * 16 + lr) * 72 + kof + lk8];
#pragma unroll
            for (int jj = 0; jj < 2; jj++)
                ub[jj] = *(const s16x8*)&shA[(wc * 32 + jj * 16 + lr) * 136 + half * 64 + kof + lk8];
#pragma unroll
            for (int i = 0; i < 4; i++)
#pragma unroll
                for (int jj = 0; jj < 2; jj++)
                    acc2[i][jj] = __builtin_amdgcn_mfma_f32_16x16x32_bf16(pa[i], ub[jj], acc2[i][jj], 0, 0, 0);
        }
        __syncthreads();
    }

    // ---- y_intra store: f32 repack in shB, then vector u16x8 stores
    {
        float* fb = (float*)shB;   // 128 x 68 f32 = 34816 B = sizeof(shB)
#pragma unroll
        for (int i = 0; i < 4; i++)
#pragma unroll
            for (int jj = 0; jj < 2; jj++)
#pragma unroll
                for (int r = 0; r < 4; r++) {
                    int row = wr * 64 + i * 16 + (l >> 4) * 4 + r;
                    fb[row * 68 + wc * 32 + jj * 16 + (l & 15)] = acc2[i][jj][r];
                }
        __syncthreads();
#pragma unroll
        for (int it = 0; it < 4; it++) {
            int vv = it * 256 + t;            // 128*64/8 = 1024 vectors
            int row = vv >> 3, col = (vv & 7) * 8;
            float4 f0 = *(const float4*)&fb[row * 68 + col];
            float4 f1 = *(const float4*)&fb[row * 68 + col + 4];
            s16x8 ov;
            const float* p0 = (const float*)&f0;
            const float* p1 = (const float*)&f1;
#pragma unroll
            for (int j = 0; j < 4; j++) { ov[j] = (short)f2bf(p0[j]); ov[4 + j] = (short)f2bf(p1[j]); }
            *(s16x8*)&y16[(row0 + row) * 1024 + h * 64 + col] = ov;
        }
        __syncthreads();
    }

    // ---- BTw build: BTw[n][j] = wv[j]*B[j][n]; vectorized u16x8 global reads
    {
        int j = t >> 1;                        // 0..127
        int nh = (t & 1) * 64;                 // n half
        float wj = wv[j];
        const u16* src = bcbf + (row0 + j) * 256 + nh;
#pragma unroll
        for (int vq = 0; vq < 8; vq++) {
            s16x8 vec = *(const s16x8*)(src + vq * 8);
            int n0 = nh + vq * 8;
#pragma unroll
            for (int i = 0; i < 8; i++)
                shB[(n0 + i) * 136 + j] = f2bf(wj * bf2f((u16)vec[i]));
        }
    }
    __syncthreads();

    // ---- phase 3: Sc = UT.(BTw) -> bf16 [p][128]
    f32x4 acc3[4][2] = {};
#pragma unroll
    for (int ks = 0; ks < 4; ks++) {
        int kof = ks * 32;
        s16x8 ua[4], bb[2];
#pragma unroll
        for (int i = 0; i < 4; i++)
            ua[i] = *(const s16x8*)&shA[(i * 16 + lr) * 136 + kof + lk8];
#pragma unroll
        for (int jj = 0; jj < 2; jj++)
            bb[jj] = *(const s16x8*)&shB[(w * 32 + jj * 16 + lr) * 136 + kof + lk8];
#pragma unroll
        for (int i = 0; i < 4; i++)
#pragma unroll
            for (int jj = 0; jj < 2; jj++)
                acc3[i][jj] = __builtin_amdgcn_mfma_f32_16x16x32_bf16(ua[i], bb[jj], acc3[i][jj], 0, 0, 0);
    }
#pragma unroll
    for (int i = 0; i < 4; i++)
#pragma unroll
        for (int jj = 0; jj < 2; jj++) {
            int n = w * 32 + jj * 16 + (l & 15);
#pragma unroll
            for (int r = 0; r < 4; r++) {
                int p = i * 16 + (l >> 4) * 4 + r;
                scb16[(size_t)bhc * 8192 + (size_t)p * 128 + n] = f2bf(acc3[i][jj][r]);
            }
        }
}

// sequential chunk-state recurrence (bf16 in/out, f32 accumulate)
// 256 blocks x 256 thr: block = (b*16+h)*2 + seg; each block owns half the
// (p,n) state vector -> full CU coverage (was 128 blocks = half the chip)
__global__ __launch_bounds__(256) void k_states(u16* __restrict__ scb16,
                                                const float* __restrict__ elbuf) {
    int bh  = blockIdx.x >> 1;            // b*16+h
    int seg = blockIdx.x & 1;
    int t = threadIdx.x;
    float hreg[16];
#pragma unroll
    for (int j = 0; j < 16; j++) hreg[j] = 0.f;
    size_t o = (size_t)(seg * 256 + t) * 16;
    for (int c = 0; c < 8; c++) {
        int bhc = bh * 8 + c;
        float Tc = elbuf[(size_t)bhc * 128 + 127];
        u16* p = scb16 + (size_t)bhc * 8192 + o;
        s16x8 v0 = *(s16x8*)(p);
        s16x8 v1 = *(s16x8*)(p + 8);
        s16x8 o0, o1;
#pragma unroll
        for (int j = 0; j < 8; j++) {
            o0[j] = (short)f2bf(hreg[j]);
            o1[j] = (short)f2bf(hreg[8 + j]);
        }
        *(s16x8*)(p)     = o0;
        *(s16x8*)(p + 8) = o1;
#pragma unroll
        for (int j = 0; j < 8; j++) {
            hreg[j]     = fmaf(Tc, hreg[j],     bf2f((u16)v0[j]));
            hreg[8 + j] = fmaf(Tc, hreg[8 + j], bf2f((u16)v1[j]));
        }
    }
}

// ============ inter-chunk: pipelined stages + vector RMW epilogue ============
#define INT_STAGE(bf_, k0_) do {                                                \
    _Pragma("unroll")                                                           \
    for (int s_ = 0; s_ < 2; s_++) {                                            \
        int g_ = w * 2 + s_;                                                    \
        GLOAD_LDS16(bcbf + (row0 + g_ * 16 + lr) * 256 + 128 + (k0_) + lk8,     \
                    &CStg[bf_][g_ * 512]);                                      \
    }                                                                           \
    GLOAD_LDS16(scb16 + (size_t)bhc * 8192 + (size_t)(w * 16 + lr) * 128 + (k0_) + lk8, \
                &HStg[bf_][w * 512]);                                           \
    } while (0)

__global__ __launch_bounds__(256) void k_inter(
    const u16* __restrict__ xhbf, const u16* __restrict__ bcbf,
    const float* __restrict__ elbuf, const u16* __restrict__ scb16,
    const float* __restrict__ Dp, u16* __restrict__ y16) {
    int bid = blockIdx.x;
    int bhc = (bid & 7) * 128 + (bid >> 3);
    int c = bhc & 7, h = (bhc >> 3) & 15, b = bhc >> 7;
    const size_t row0 = (size_t)b * 1024 + c * 128;
    const int t = threadIdx.x, w = t >> 6, l = t & 63;
    const int wr = w >> 1, wc = w & 1;
    const int lr = l & 15, lk8 = (l >> 4) * 8;
    __shared__ __align__(16) u16 CStg[2][4096];
    __shared__ __align__(16) u16 HStg[2][2048];
    __shared__ __align__(16) float FY[64 * 68];
    __shared__ float el[128];
    float Dv = Dp[h];
    float elv = (t < 128) ? elbuf[(size_t)bhc * 128 + t] : 0.f;

    INT_STAGE(0, 0);
    INT_STAGE(1, 32);
    if (t < 128) el[t] = elv;

    f32x4 acc[4][2] = {};
    for (int ks = 0; ks < 4; ks++) {
        int cur = ks & 1;
        if (ks < 3) asm volatile("s_waitcnt vmcnt(3)" ::: "memory");
        else        asm volatile("s_waitcnt vmcnt(0)" ::: "memory");
        __builtin_amdgcn_s_barrier();
        s16x8 ca[4], hb[2];
#pragma unroll
        for (int i = 0; i < 4; i++)
            ca[i] = *(const s16x8*)&CStg[cur][(wr * 4 + i) * 512 + l * 8];
#pragma unroll
        for (int jj = 0; jj < 2; jj++)
            hb[jj] = *(const s16x8*)&HStg[cur][(wc * 2 + jj) * 512 + l * 8];
#pragma unroll
        for (int i = 0; i < 4; i++)
#pragma unroll
            for (int jj = 0; jj < 2; jj++)
                acc[i][jj] = __builtin_amdgcn_mfma_f32_16x16x32_bf16(ca[i], hb[jj], acc[i][jj], 0, 0, 0);
        __builtin_amdgcn_s_barrier();
        if (ks + 2 < 4) INT_STAGE(cur, (ks + 2) * 32);
    }

    // epilogue: chunked f32 repack (rows ch*64..) -> vector RMW
    for (int ch = 0; ch < 2; ch++) {
        if (wr == ch) {
#pragma unroll
            for (int i = 0; i < 4; i++)
#pragma unroll
                for (int jj = 0; jj < 2; jj++)
#pragma unroll
                    for (int r = 0; r < 4; r++) {
                        int rrow = i * 16 + (l >> 4) * 4 + r;   // 0..63
                        FY[rrow * 68 + wc * 32 + jj * 16 + (l & 15)] =
                            el[ch * 64 + rrow] * acc[i][jj][r];
                    }
        }
        __syncthreads();
#pragma unroll
        for (int it = 0; it < 2; it++) {
            int vv = it * 256 + t;            // 64*64/8 = 512 vectors
            int row = vv >> 3, col = (vv & 7) * 8;
            float4 f0 = *(const float4*)&FY[row * 68 + col];
            float4 f1 = *(const float4*)&FY[row * 68 + col + 4];
            size_t yo = (row0 + ch * 64 + row) * 1024 + h * 64 + col;
            s16x8 yv = *(const s16x8*)&y16[yo];
            s16x8 xv = *(const s16x8*)&xhbf[yo];
            s16x8 ov;
            const float* p0 = (const float*)&f0;
            const float* p1 = (const float*)&f1;
#pragma unroll
            for (int j = 0; j < 4; j++) {
                ov[j]     = (short)f2bf(bf2f((u16)yv[j])     + p0[j] + Dv * bf2f((u16)xv[j]));
                ov[4 + j] = (short)f2bf(bf2f((u16)yv[4 + j]) + p1[j] + Dv * bf2f((u16)xv[4 + j]));
            }
            *(s16x8*)&y16[yo] = ov;
        }
        __syncthreads();
    }
}

// ---------------- gate: ybf = bf16(rmsnorm(y * silu(z)) * norm_w) ----------------
__global__ __launch_bounds__(256) void k_gate(
    const u16* __restrict__ y16, const u16* __restrict__ zbf,
    const float* __restrict__ nw, u16* __restrict__ ybf) {
    __shared__ float sbuf[4];
    int bl = blockIdx.x;
    int t  = threadIdx.x;
    u16x4 yv4 = *(const u16x4*)(y16 + (size_t)bl * 1024 + t * 4);
    u16x4 zv4 = *(const u16x4*)(zbf + (size_t)bl * 1024 + t * 4);
    float4 gv;
    gv.x = bf2f(yv4.x) * siluf(bf2f(zv4.x));
    gv.y = bf2f(yv4.y) * siluf(bf2f(zv4.y));
    gv.z = bf2f(yv4.z) * siluf(bf2f(zv4.z));
    gv.w = bf2f(yv4.w) * siluf(bf2f(zv4.w));
    float q = gv.x * gv.x + gv.y * gv.y + gv.z * gv.z + gv.w * gv.w;
    for (int off = 32; off; off >>= 1) q += __shfl_xor(q, off, 64);
    int wid = t >> 6, lane = t & 63;
    if (lane == 0) sbuf[wid] = q;
    __syncthreads();
    float tot = sbuf[0] + sbuf[1] + sbuf[2] + sbuf[3];
    float scale = 1.0f / sqrtf(tot * (1.f / 1024.f) + EPS);
    float4 nv = *(const float4*)(nw + t * 4);
    float4 o;
    o.x = gv.x * scale * nv.x;
    o.y = gv.y * scale * nv.y;
    o.z = gv.z * scale * nv.z;
    o.w = gv.w * scale * nv.w;
    *(u16x4*)(ybf + (size_t)bl * 1024 + t * 4) = f2bf4(o);
}

// ---------------- pool stage 1 (bf16 input) ----------------
__global__ __launch_bounds__(256) void k_pool1(const u16* __restrict__ xbf,
                                               float* __restrict__ psum,
                                               float* __restrict__ pmax) {
    int blk = blockIdx.x;          // b*64 + lc
    int b = blk >> 6, lc = blk & 63;
    int t = threadIdx.x;
    const u16* px = xbf + (size_t)b * 524288 + (size_t)lc * 16 * 512;
    float s0 = 0.f, s1 = 0.f, m0 = -3.0e38f, m1 = -3.0e38f;
#pragma unroll
    for (int r = 0; r < 16; r++) {
        float v0 = bf2f(px[r * 512 + t]);
        float v1 = bf2f(px[r * 512 + t + 256]);
        s0 += v0; s1 += v1;
        m0 = fmaxf(m0, v0); m1 = fmaxf(m1, v1);
    }
    psum[(size_t)blk * 512 + t]       = s0;
    psum[(size_t)blk * 512 + t + 256] = s1;
    pmax[(size_t)blk * 512 + t]       = m0;
    pmax[(size_t)blk * 512 + t + 256] = m1;
}

// ---------------- pool stage 2 ----------------
__global__ __launch_bounds__(256) void k_pool2(const float* __restrict__ psum,
                                               const float* __restrict__ pmax,
                                               float* __restrict__ pooled) {
    int idx = blockIdx.x * 256 + threadIdx.x;   // 4096 exact
    int b = idx >> 9, d = idx & 511;
    float s = 0.f, m = -3.0e38f;
    for (int c = 0; c < 64; c++) {
        s += psum[((size_t)b * 64 + c) * 512 + d];
        m = fmaxf(m, pmax[((size_t)b * 64 + c) * 512 + d]);
    }
    pooled[idx] = 0.5f * (s * (1.f / 1024.f) + m);
}

// ---------------- small FC ----------------
template <int ACT>
__global__ void k_fc(const float* __restrict__ in, const float* __restrict__ W,
                     const float* __restrict__ bias, float* __restrict__ out,
                     int BN, int N, int K) {
    int idx = blockIdx.x * 64 + threadIdx.x;
    if (idx >= BN) return;
    int b = idx / N, n = idx % N;
    const float* a = in + (size_t)b * K;
    const float* w = W + (size_t)n * K;
    float acc = 0.f;
    for (int k = 0; k < K; k += 4) {
        float4 av = *(const float4*)(a + k);
        float4 wv = *(const float4*)(w + k);
        acc += av.x * wv.x + av.y * wv.y + av.z * wv.z + av.w * wv.w;
    }
    float v = acc + bias[n];
    if (ACT == 1) v = geluf(v);
    out[idx] = v;
}

extern "C" void kernel_launch(void* const* d_in, const int* in_sizes, int n_in,
                              void* d_out, int out_size, void* d_ws, size_t ws_size,
                              hipStream_t stream) {
    (void)in_sizes; (void)n_in; (void)out_size; (void)ws_size;
    const int*   tok        = (const int*)  d_in[0];
    const float* mask       = (const float*)d_in[1];
    const float* emb        = (const float*)d_in[2];
    const float* pos        = (const float*)d_in[3];
    const float* inp_w      = (const float*)d_in[4];
    const float* inp_b      = (const float*)d_in[5];
    const float* ln_g       = (const float*)d_in[6];
    const float* ln_b       = (const float*)d_in[7];
    const float* in_proj_w  = (const float*)d_in[8];
    const float* conv_w     = (const float*)d_in[9];
    const float* conv_b     = (const float*)d_in[10];
    const float* dt_bias    = (const float*)d_in[11];
    const float* A_log      = (const float*)d_in[12];
    const float* Dparam     = (const float*)d_in[13];
    const float* norm_w     = (const float*)d_in[14];
    const float* out_proj_w = (const float*)d_in[15];
    const float* pooler_w   = (const float*)d_in[16];
    const float* pooler_b   = (const float*)d_in[17];
    const float* cls_w1     = (const float*)d_in[18];
    const float* cls_b1     = (const float*)d_in[19];
    const float* cls_w2     = (const float*)d_in[20];
    const float* cls_b2     = (const float*)d_in[21];
    float* out = (float*)d_out;

    float* ws     = (float*)d_ws;
    float* x      = ws;                                // 8192*512 (prologue only)
    float* dt_raw = x + (size_t)8192 * 512;            // 8192*16
    float* elbuf  = dt_raw + (size_t)8192 * 16;        // 131072
    float* psum   = elbuf + 131072;                    // 262144
    float* pmax   = psum + 262144;                     // 262144
    float* pooled = pmax + 262144;                     // 4096
    float* pbuf   = pooled + 4096;                     // 4096
    float* cbuf   = pbuf + 4096;                       // 2048
    u16* x_bf    = (u16*)(cbuf + 2048);                // 8192*512 (bf16 residual)
    u16* z_bf    = x_bf + (size_t)8192 * 512;          // 8192*1024
    u16* xbc_in  = z_bf + (size_t)8192 * 1024;         // 8192*1280 (conv input bf16)
    u16* y_bf    = xbc_in + (size_t)8192 * 1280;       // 8192*1024 (gate out)
    u16* xhbf    = y_bf + (size_t)8192 * 1024;         // 8192*1024
    u16* bcbf    = xhbf + (size_t)8192 * 1024;         // 8192*256
    u16* y16     = bcbf + (size_t)8192 * 256;          // 8192*1024 (SSM out, bf16)
    u16* wip_bf  = y16 + (size_t)8192 * 1024;          // 4*2432*512
    u16* wop_bf  = wip_bf + (size_t)4 * 2432 * 512;    // 4*512*1024
    u16* winp_bf = wop_bf + (size_t)4 * 512 * 1024;    // 512*512
    // overlays in dead windows:
    u16* xe_bf   = (u16*)y16;                          // prologue only (y16 dead)
    u16* scb16   = xbc_in;                             // over xbc_in (dead between
                                                       // k_ssd and next in_proj)

    // merged weight casts (single dispatch)
    k_casts<<<7168, 256, 0, stream>>>(in_proj_w, out_proj_w, inp_w,
                                      wip_bf, wop_bf, winp_bf);

    // embedding + positional (bf16)
    k_embed<<<4096, 256, 0, stream>>>(tok, emb, pos, xe_bf);
    // x = embed @ inp_w^T + inp_b  (fp32, prologue only)
    k_gemm_mfma<1><<<256, 512, 0, stream>>>(xe_bf, winp_bf, inp_b, x, nullptr,
                                            nullptr, 8192, 512, 512, 4);
    // LN -> bf16 residual stream x_bf
    k_layernorm<<<8192, 128, 0, stream>>>(x, ln_g, ln_b, mask, x_bf);

    for (int i = 0; i < 4; i++) {
        // split in_proj: z_bf | xbc_in (bf16) | dt_raw (f32); 256x128 tile
        k_gemm_in<<<608, 512, 0, stream>>>(x_bf, wip_bf + (size_t)i * 2432 * 512,
                                           z_bf, xbc_in, dt_raw);
        k_conv<<<8192, 320, 0, stream>>>(xbc_in, conv_w + (size_t)i * 1280 * 4,
                                         conv_b + (size_t)i * 1280, xhbf, bcbf);
        k_ssd<<<1024, 256, 0, stream>>>(xhbf, bcbf, dt_raw, dt_bias + i * 16,
                                        A_log + i * 16, elbuf, y16, scb16);
        k_states<<<256, 256, 0, stream>>>(scb16, elbuf);
        k_inter<<<1024, 256, 0, stream>>>(xhbf, bcbf, elbuf, scb16,
                                          Dparam + (size_t)i * 16, y16);
        k_gate<<<8192, 256, 0, stream>>>(y16, z_bf, norm_w + (size_t)i * 1024, y_bf);
        // x_bf = bf16((x_bf + y @ out_proj_w[i]^T) * mask)   (bf16 residual RMW)
        k_gemm_mfma<2><<<256, 512, 0, stream>>>(y_bf, wop_bf + (size_t)i * 512 * 1024,
                                                nullptr, nullptr, x_bf, mask,
                                                8192, 512, 1024, 4);
    }

    k_pool1<<<512, 256, 0, stream>>>(x_bf, psum, pmax);
    k_pool2<<<16, 256, 0, stream>>>(psum, pmax, pooled);
    k_fc<1><<<64, 64, 0, stream>>>(pooled, pooler_w, pooler_b, pbuf, 8 * 512, 512, 512);
    k_fc<1><<<32, 64, 0, stream>>>(pbuf, cls_w1, cls_b1, cbuf, 8 * 256, 256, 512);
    k_fc<0><<<1, 64, 0, stream>>>(cbuf, cls_w2, cls_b2, out, 8 * 2, 2, 256);
}

// Round 22
// 808.519 us; speedup vs baseline: 1.0160x; 1.0026x over previous
//
#include <hip/hip_runtime.h>

#define EPS 1e-5f
typedef unsigned short u16;
typedef short s16x8 __attribute__((ext_vector_type(8)));
typedef float f32x4 __attribute__((ext_vector_type(4)));

__device__ __forceinline__ float siluf(float x) { return x / (1.0f + __expf(-x)); }
__device__ __forceinline__ float geluf(float x) {
    float u = 0.7978845608028654f * (x + 0.044715f * x * x * x);
    return 0.5f * x * (1.0f + tanhf(u));
}
__device__ __forceinline__ u16 f2bf(float f) {
    unsigned u = __float_as_uint(f);
    return (u16)((u + 0x7fffu + ((u >> 16) & 1u)) >> 16);
}
__device__ __forceinline__ float bf2f(u16 v) {
    return __uint_as_float(((unsigned)v) << 16);
}
struct u16x4 { u16 x, y, z, w; };
__device__ __forceinline__ u16x4 f2bf4(float4 v) {
    u16x4 r; r.x = f2bf(v.x); r.y = f2bf(v.y); r.z = f2bf(v.z); r.w = f2bf(v.w);
    return r;
}

#define GLOAD_LDS16(gp, lp) __builtin_amdgcn_global_load_lds( \
    (const __attribute__((address_space(1))) void*)(gp),      \
    (__attribute__((address_space(3))) void*)(lp), 16, 0, 0)

// ------- merged weight casts + embedding (one dispatch, disjoint work) -------
__global__ void k_casts(const float* __restrict__ ip, const float* __restrict__ op,
                        const float* __restrict__ inp, u16* __restrict__ wip,
                        u16* __restrict__ wop, u16* __restrict__ winp,
                        const int* __restrict__ tok, const float* __restrict__ emb,
                        const float* __restrict__ pos, u16* __restrict__ xe) {
    int idx = blockIdx.x * 256 + threadIdx.x;   // 1835008 casts + 1048576 embed
    if (idx < 1245184) {                        // in_proj, zero-pad rows >= 2320
        int e4 = idx * 4;
        int layer = e4 / 1245184;
        int rem   = e4 - layer * 1245184;
        int row   = rem >> 9;
        int k     = rem & 511;
        float4 v = make_float4(0.f, 0.f, 0.f, 0.f);
        if (row < 2320)
            v = *(const float4*)(ip + (size_t)layer * 1187840 + (size_t)row * 512 + k);
        *(u16x4*)(wip + e4) = f2bf4(v);
    } else if (idx < 1245184 + 524288) {        // out_proj
        int j = idx - 1245184;
        float4 v = *(const float4*)(op + (size_t)j * 4);
        *(u16x4*)(wop + (size_t)j * 4) = f2bf4(v);
    } else if (idx < 1245184 + 524288 + 65536) {  // inp
        int j = idx - 1245184 - 524288;
        float4 v = *(const float4*)(inp + (size_t)j * 4);
        *(u16x4*)(winp + (size_t)j * 4) = f2bf4(v);
    } else if (idx < 1835008 + 1048576) {       // embedding + positional -> bf16
        int j = idx - 1835008;
        int d4 = j & 127;
        int bl = j >> 7;
        int l  = bl & 1023;
        float4 e = *(const float4*)(emb + tok[bl] * 512 + d4 * 4);
        float4 p = *(const float4*)(pos + l * 512 + d4 * 4);
        float4 v = make_float4(e.x + p.x, e.y + p.y, e.z + p.z, e.w + p.w);
        *(u16x4*)(xe + (size_t)j * 4) = f2bf4(v);
    }
}

// ===== in_proj GEMM: 256x128 tile, 512 thr, wave-tile 64x64, 3-buf depth-2 ====
#define STAGE_I(buf, k0) do {                                                   \
    _Pragma("unroll")                                                           \
    for (int s_ = 0; s_ < 2; s_++) {                                            \
        int g_ = w * 2 + s_;                                                    \
        GLOAD_LDS16(A + (size_t)(m0 + g_ * 16 + lr) * 512 + (k0) + lk,          \
                    smem + (buf) * 8192 + g_ * 512);                            \
    }                                                                           \
    GLOAD_LDS16(B + (size_t)(n0 + w * 16 + lr) * 512 + (k0) + lk,               \
                smem + 24576 + (buf) * 4096 + w * 512);                         \
    } while (0)

#define COMPUTE_I(buf) do {                                                     \
    s16x8 af_[4], bf_[4];                                                       \
    _Pragma("unroll")                                                           \
    for (int i_ = 0; i_ < 4; i_++) {                                            \
        af_[i_] = *(const s16x8*)&smem[(buf) * 8192 + (wr * 4 + i_) * 512 + l * 8]; \
        bf_[i_] = *(const s16x8*)&smem[24576 + (buf) * 4096 + (wc * 4 + i_) * 512 + l * 8]; \
    }                                                                           \
    _Pragma("unroll")                                                           \
    for (int i_ = 0; i_ < 4; i_++)                                              \
        _Pragma("unroll")                                                       \
        for (int j_ = 0; j_ < 4; j_++)                                          \
            acc[i_][j_] = __builtin_amdgcn_mfma_f32_16x16x32_bf16(              \
                af_[i_], bf_[j_], acc[i_][j_], 0, 0, 0);                        \
    } while (0)

__global__ __launch_bounds__(512, 4) void k_gemm_in(
    const u16* __restrict__ A, const u16* __restrict__ B,
    u16* __restrict__ zbf, u16* __restrict__ xbcbf, float* __restrict__ dtw) {
    __shared__ __align__(16) u16 smem[36864];   // 3x8192 A | 3x4096 B; ep 256x136
    const int t = threadIdx.x;
    const int w = t >> 6, l = t & 63;
    const int wr = w >> 1, wc = w & 1;          // 4x2 wave grid, wave-tile 64x64
    const int lr = l & 15, lk = (l >> 4) * 8;
    const int wgid = (blockIdx.x & 7) * 76 + (blockIdx.x >> 3);  // 608 = 8*76
    const int m0 = (wgid / 19) * 256;
    const int nt = wgid % 19;
    const int n0 = nt * 128;

    f32x4 acc[4][4] = {};

    STAGE_I(0, 0);
    STAGE_I(1, 32);
    for (int ki = 0; ki < 14; ki++) {           // nk = 16
        asm volatile("s_waitcnt vmcnt(3)" ::: "memory");
        __builtin_amdgcn_s_barrier();
        STAGE_I((ki + 2) % 3, (ki + 2) * 32);
        COMPUTE_I(ki % 3);
    }
    asm volatile("s_waitcnt vmcnt(3)" ::: "memory");
    __builtin_amdgcn_s_barrier();
    COMPUTE_I(14 % 3);
    asm volatile("s_waitcnt vmcnt(0)" ::: "memory");
    __builtin_amdgcn_s_barrier();
    COMPUTE_I(15 % 3);
    __syncthreads();

    if (nt < 18) {
        // repack to LDS (bf16), then coalesced u16x8 stores
#pragma unroll
        for (int i = 0; i < 4; i++)
#pragma unroll
            for (int j = 0; j < 4; j++)
#pragma unroll
                for (int r2 = 0; r2 < 4; r2++) {
                    int erow = wr * 64 + i * 16 + (l >> 4) * 4 + r2;
                    int ecol = wc * 64 + j * 16 + (l & 15);
                    smem[erow * 136 + ecol] = f2bf(acc[i][j][r2]);
                }
        __syncthreads();
        if (nt < 8) {
#pragma unroll
            for (int it = 0; it < 8; it++) {
                int v = it * 512 + t;
                int row = v >> 4, col = (v & 15) * 8;
                *(s16x8*)&zbf[(size_t)(m0 + row) * 1024 + n0 + col] =
                    *(const s16x8*)&smem[row * 136 + col];
            }
        } else {
            int nb = n0 - 1024;
#pragma unroll
            for (int it = 0; it < 8; it++) {
                int v = it * 512 + t;
                int row = v >> 4, col = (v & 15) * 8;
                *(s16x8*)&xbcbf[(size_t)(m0 + row) * 1280 + nb + col] =
                    *(const s16x8*)&smem[row * 136 + col];
            }
        }
    } else {
        // dt tile (cols 2304..2319 live, rest zero-pad)
#pragma unroll
        for (int i = 0; i < 4; i++) {
            int mb = m0 + wr * 64 + i * 16 + (l >> 4) * 4;
#pragma unroll
            for (int j = 0; j < 4; j++) {
                int n = n0 + wc * 64 + j * 16 + (l & 15);
#pragma unroll
                for (int r2 = 0; r2 < 4; r2++) {
                    if (n < 2320)
                        dtw[(size_t)(mb + r2) * 16 + (n - 2304)] = acc[i][j][r2];
                }
            }
        }
    }
}

// --- generic MFMA GEMM NT: 512 thr, wave-tile 64x32, 3-buf depth-2 -----------
// MODE 1: C = acc + bias[n] (f32)
// MODE 2: Cbf = bf16((bf2f(Cbf) + acc) * mask[m])   (bf16 residual RMW)
#define STAGE(buf, k0) do {                                                     \
    GLOAD_LDS16(A + (size_t)(m0 + w * 16 + lr) * K + (k0) + lk,                 \
                &Asm[buf][w * 512]);                                            \
    GLOAD_LDS16(B + (size_t)(n0 + w * 16 + lr) * K + (k0) + lk,                 \
                &Bsm[buf][w * 512]);                                            \
    } while (0)

#define COMPUTE(buf) do {                                                       \
    s16x8 af_[4], bf_[2];                                                       \
    _Pragma("unroll")                                                           \
    for (int i_ = 0; i_ < 4; i_++)                                              \
        af_[i_] = *(const s16x8*)&Asm[buf][(wr * 4 + i_) * 512 + l * 8];        \
    _Pragma("unroll")                                                           \
    for (int j_ = 0; j_ < 2; j_++)                                              \
        bf_[j_] = *(const s16x8*)&Bsm[buf][(wc * 2 + j_) * 512 + l * 8];        \
    _Pragma("unroll")                                                           \
    for (int i_ = 0; i_ < 4; i_++)                                              \
        _Pragma("unroll")                                                       \
        for (int j_ = 0; j_ < 2; j_++)                                          \
            acc[i_][j_] = __builtin_amdgcn_mfma_f32_16x16x32_bf16(              \
                af_[i_], bf_[j_], acc[i_][j_], 0, 0, 0);                        \
    } while (0)

template <int MODE>
__global__ __launch_bounds__(512) void k_gemm_mfma(
    const u16* __restrict__ A, const u16* __restrict__ B,
    const float* __restrict__ bias, float* __restrict__ C,
    u16* __restrict__ Cbf, const float* __restrict__ mask,
    int M, int N, int K, int gx) {
    __shared__ u16 Asm[3][4096];
    __shared__ u16 Bsm[3][4096];
    const int t = threadIdx.x;
    const int w = t >> 6, l = t & 63;
    const int wr = w >> 2, wc = w & 3;          // 2x4 wave grid, wave-tile 64x32
    const int lr = l & 15, lk = (l >> 4) * 8;
    const int nwg = gridDim.x;
    const int q = nwg >> 3, r = nwg & 7;
    const int x8 = blockIdx.x & 7, d8 = blockIdx.x >> 3;
    const int wgid = (x8 < r) ? x8 * (q + 1) + d8 : r * (q + 1) + (x8 - r) * q + d8;
    const int m0 = (wgid / gx) * 128;
    const int n0 = (wgid % gx) * 128;

    f32x4 acc[4][2] = {};

    const int nk = K >> 5;
    STAGE(0, 0);
    STAGE(1, 32);
    for (int ki = 0; ki < nk - 2; ki++) {
        asm volatile("s_waitcnt vmcnt(2)" ::: "memory");
        __builtin_amdgcn_s_barrier();
        STAGE((ki + 2) % 3, (ki + 2) * 32);
        COMPUTE(ki % 3);
    }
    asm volatile("s_waitcnt vmcnt(2)" ::: "memory");
    __builtin_amdgcn_s_barrier();
    COMPUTE((nk - 2) % 3);
    asm volatile("s_waitcnt vmcnt(0)" ::: "memory");
    __builtin_amdgcn_s_barrier();
    COMPUTE((nk - 1) % 3);

#pragma unroll
    for (int i = 0; i < 4; i++) {
        int mb = m0 + wr * 64 + i * 16 + (l >> 4) * 4;
#pragma unroll
        for (int j = 0; j < 2; j++) {
            int n = n0 + wc * 32 + j * 16 + (l & 15);
#pragma unroll
            for (int r2 = 0; r2 < 4; r2++) {
                int m = mb + r2;
                float v = acc[i][j][r2];
                if (n < N) {
                    size_t o = (size_t)m * N + n;
                    if (MODE == 1) {
                        C[o] = v + bias[n];
                    } else {
                        float v2 = (bf2f(Cbf[o]) + v) * mask[m];
                        Cbf[o] = f2bf(v2);
                    }
                }
            }
        }
    }
}

// ---------------- LayerNorm + mask -> bf16 only ----------------
__global__ __launch_bounds__(128) void k_layernorm(
    const float* __restrict__ x, const float* __restrict__ g,
    const float* __restrict__ b, const float* __restrict__ mask,
    u16* __restrict__ xbf) {
    __shared__ float2 sbuf[2];
    int bl = blockIdx.x;
    int t  = threadIdx.x;
    float4 v = *(const float4*)(x + (size_t)bl * 512 + t * 4);
    float s = v.x + v.y + v.z + v.w;
    float q = v.x * v.x + v.y * v.y + v.z * v.z + v.w * v.w;
    for (int off = 32; off; off >>= 1) {
        s += __shfl_xor(s, off, 64);
        q += __shfl_xor(q, off, 64);
    }
    int wid = t >> 6, lane = t & 63;
    if (lane == 0) sbuf[wid] = make_float2(s, q);
    __syncthreads();
    float ts = sbuf[0].x + sbuf[1].x;
    float tq = sbuf[0].y + sbuf[1].y;
    float mu  = ts * (1.f / 512.f);
    float var = tq * (1.f / 512.f) - mu * mu;
    float inv = 1.0f / sqrtf(var + EPS);
    float mk  = mask[bl];
    float4 gg = *(const float4*)(g + t * 4);
    float4 bb = *(const float4*)(b + t * 4);
    float4 o;
    o.x = ((v.x - mu) * inv * gg.x + bb.x) * mk;
    o.y = ((v.y - mu) * inv * gg.y + bb.y) * mk;
    o.z = ((v.z - mu) * inv * gg.z + bb.z) * mk;
    o.w = ((v.w - mu) * inv * gg.w + bb.w) * mk;
    *(u16x4*)(xbf + (size_t)bl * 512 + t * 4) = f2bf4(o);
}

// --- causal depthwise conv (k=4, bf16 in) + bias + SiLU -> bf16 (xh | B/C) ---
__global__ __launch_bounds__(320) void k_conv(
    const u16* __restrict__ xbc_in, const float* __restrict__ cw,
    const float* __restrict__ cb, u16* __restrict__ xhbf,
    u16* __restrict__ bcbf) {
    int bid = blockIdx.x;
    int bl = (bid & 7) * 1024 + (bid >> 3);    // 8192 rows, bijective
    int l  = bl & 1023;
    int c  = threadIdx.x * 4;
    float4 w0 = *(const float4*)(cw + (c + 0) * 4);
    float4 w1 = *(const float4*)(cw + (c + 1) * 4);
    float4 w2 = *(const float4*)(cw + (c + 2) * 4);
    float4 w3 = *(const float4*)(cw + (c + 3) * 4);
    float4 a  = *(const float4*)(cb + c);
#pragma unroll
    for (int k = 0; k < 4; k++) {
        if (l + k - 3 >= 0) {
            u16x4 v = *(const u16x4*)(xbc_in + (size_t)(bl + k - 3) * 1280 + c);
            const float* wk0 = (const float*)&w0;
            const float* wk1 = (const float*)&w1;
            const float* wk2 = (const float*)&w2;
            const float* wk3 = (const float*)&w3;
            a.x = fmaf(bf2f(v.x), wk0[k], a.x);
            a.y = fmaf(bf2f(v.y), wk1[k], a.y);
            a.z = fmaf(bf2f(v.z), wk2[k], a.z);
            a.w = fmaf(bf2f(v.w), wk3[k], a.w);
        }
    }
    float4 o = make_float4(siluf(a.x), siluf(a.y), siluf(a.z), siluf(a.w));
    if (c < 1024)
        *(u16x4*)(xhbf + (size_t)bl * 1024 + c) = f2bf4(o);
    else
        *(u16x4*)(bcbf + (size_t)bl * 256 + (c - 1024)) = f2bf4(o);
}

// ============ fused SSD intra (r12 layout; vectorized UT/BTw global reads) ====
#define SSD_STAGE(dst, k0) do {                                                 \
    _Pragma("unroll")                                                           \
    for (int s_ = 0; s_ < 2; s_++) {                                            \
        int g_ = w * 2 + s_;                                                    \
        GLOAD_LDS16(bcbf + (row0 + g_ * 16 + lr) * 256 + 128 + (k0) + lk8,      \
                    (dst) + g_ * 512);                                          \
        GLOAD_LDS16(bcbf + (row0 + g_ * 16 + lr) * 256 + (k0) + lk8,            \
                    (dst) + 4096 + g_ * 512);                                   \
    } } while (0)

__global__ __launch_bounds__(256) void k_ssd(
    const u16* __restrict__ xhbf, const u16* __restrict__ bcbf,
    const float* __restrict__ dt_raw, const float* __restrict__ dtbias,
    const float* __restrict__ alog, float* __restrict__ elbuf,
    u16* __restrict__ y16, u16* __restrict__ scb16) {
    int bid = blockIdx.x;
    int bhc = (bid & 7) * 128 + (bid >> 3);   // bijective; batch b stays on one XCD
    int c = bhc & 7, h = (bhc >> 3) & 15, b = bhc >> 7;
    const size_t row0 = (size_t)b * 1024 + c * 128;
    const int t = threadIdx.x, w = t >> 6, l = t & 63;
    const int wr = w >> 1, wc = w & 1;
    const int lr = l & 15, lk8 = (l >> 4) * 8;

    __shared__ float cl[128], dtl[128], wv[128];
    __shared__ float csh;
    __shared__ __align__(16) u16 shA[8704];
    __shared__ __align__(16) u16 shB[17408];

    // early scalar loads, then issue phase-1 stages (DMA hides under cumsum)
    float dtb_h = dtbias[h];
    float A = -__expf(alog[h]);
    float raw = 0.f;
    if (t < 128) raw = dt_raw[(row0 + t) * 16 + h] + dtb_h;
    SSD_STAGE(shA, 0);
    SSD_STAGE(shB, 32);

    float v = 0.f;
    if (t < 128) {
        float s = (raw > 20.f) ? raw : log1pf(__expf(raw));
        dtl[t] = s;
        v = s * A;
        int lane = t & 63;
#pragma unroll
        for (int off = 1; off < 64; off <<= 1) {
            float o = __shfl_up(v, off, 64);
            if (lane >= off) v += o;
        }
        if (t == 63) csh = v;
    }
    __syncthreads();
    if (t >= 64 && t < 128) v += csh;
    if (t < 128) {
        cl[t] = v;
        elbuf[(size_t)bhc * 128 + t] = __expf(v);
    }
    __syncthreads();
    if (t < 128) wv[t] = __expf(cl[127] - cl[t]);

    // ---- phase 1: S = C.B^T (2-buf ping-pong, counted vmcnt)
    f32x4 acc[4][4] = {};
    for (int ks = 0; ks < 4; ks++) {
        u16* cur = (ks & 1) ? shB : shA;
        if (ks < 3) asm volatile("s_waitcnt vmcnt(4)" ::: "memory");
        else        asm volatile("s_waitcnt vmcnt(0)" ::: "memory");
        __builtin_amdgcn_s_barrier();
        s16x8 af[4], bfr[4];
#pragma unroll
        for (int i = 0; i < 4; i++) {
            af[i]  = *(const s16x8*)&cur[(wr * 4 + i) * 512 + l * 8];
            bfr[i] = *(const s16x8*)&cur[4096 + (wc * 4 + i) * 512 + l * 8];
        }
#pragma unroll
        for (int i = 0; i < 4; i++)
#pragma unroll
            for (int j = 0; j < 4; j++)
                acc[i][j] = __builtin_amdgcn_mfma_f32_16x16x32_bf16(af[i], bfr[j], acc[i][j], 0, 0, 0);
        __builtin_amdgcn_s_barrier();
        if (ks + 2 < 4) SSD_STAGE(cur, (ks + 2) * 32);
    }

    // ---- UT build: UT[p][j] = dt[j]*x[j][p]; vectorized u16x8 global reads
    {
        int j = t >> 1;                        // 0..127
        int ph = (t & 1) * 32;                 // p half
        float dj = dtl[j];
        const u16* src = xhbf + (row0 + j) * 1024 + h * 64 + ph;
#pragma unroll
        for (int vq = 0; vq < 4; vq++) {
            s16x8 vec = *(const s16x8*)(src + vq * 8);
            int p0 = ph + vq * 8;
#pragma unroll
            for (int i = 0; i < 8; i++)
                shA[(p0 + i) * 136 + j] = f2bf(dj * bf2f((u16)vec[i]));
        }
    }
    __syncthreads();

    // ---- phase 2: y = P.U  (P in 64-col halves)
    f32x4 acc2[4][2] = {};
    for (int half = 0; half < 2; half++) {
        if (wc == half) {
#pragma unroll
            for (int i = 0; i < 4; i++) {
#pragma unroll
                for (int j = 0; j < 4; j++) {
                    int col = half * 64 + j * 16 + (l & 15);
#pragma unroll
                    for (int r = 0; r < 4; r++) {
                        int row = wr * 64 + i * 16 + (l >> 4) * 4 + r;
                        float e = __expf(fminf(cl[row] - cl[col], 0.f));
                        float pv = (col <= row) ? acc[i][j][r] * e : 0.f;
                        shB[row * 72 + j * 16 + (l & 15)] = f2bf(pv);
                    }
                }
            }
        }
        __syncthreads();
#pragma unroll
        for (int ks = 0; ks < 2; ks++) {
            int kof = ks * 32;
            s16x8 pa[4], ub[2];
#pragma unroll
            for (int i = 0; i < 4; i++)
                pa[i] = *(const s16x8*)&shB[(wr * 64 + i * 16 + lr) * 72 + kof + lk8];
#pragma unroll
            for (int jj = 0; jj < 2; jj++)
                ub[jj] = *(const s16x8*)&shA[(wc * 32 + jj * 16 + lr) * 136 + half * 64 + kof + lk8];
#pragma unroll
            for (int i = 0; i < 4; i++)
#pragma unroll
                for (int jj = 0; jj < 2; jj++)
                    acc2[i][jj] = __builtin_amdgcn_mfma_f32_16x16x32_bf16(pa[i], ub[jj], acc2[i][jj], 0, 0, 0);
        }
        __syncthreads();
    }

    // ---- y_intra store: f32 repack in shB, then vector u16x8 stores
    {
        float* fb = (float*)shB;   // 128 x 68 f32 = 34816 B = sizeof(shB)
#pragma unroll
        for (int i = 0; i < 4; i++)
#pragma unroll
            for (int jj = 0; jj < 2; jj++)
#pragma unroll
                for (int r = 0; r < 4; r++) {
                    int row = wr * 64 + i * 16 + (l >> 4) * 4 + r;
                    fb[row * 68 + wc * 32 + jj * 16 + (l & 15)] = acc2[i][jj][r];
                }
        __syncthreads();
#pragma unroll
        for (int it = 0; it < 4; it++) {
            int vv = it * 256 + t;            // 128*64/8 = 1024 vectors
            int row = vv >> 3, col = (vv & 7) * 8;
            float4 f0 = *(const float4*)&fb[row * 68 + col];
            float4 f1 = *(const float4*)&fb[row * 68 + col + 4];
            s16x8 ov;
            const float* p0 = (const float*)&f0;
            const float* p1 = (const float*)&f1;
#pragma unroll
            for (int j = 0; j < 4; j++) { ov[j] = (short)f2bf(p0[j]); ov[4 + j] = (short)f2bf(p1[j]); }
            *(s16x8*)&y16[(row0 + row) * 1024 + h * 64 + col] = ov;
        }
        __syncthreads();
    }

    // ---- BTw build: BTw[n][j] = wv[j]*B[j][n]; vectorized u16x8 global reads
    {
        int j = t >> 1;                        // 0..127
        int nh = (t & 1) * 64;                 // n half
        float wj = wv[j];
        const u16* src = bcbf + (row0 + j) * 256 + nh;
#pragma unroll
        for (int vq = 0; vq < 8; vq++) {
            s16x8 vec = *(const s16x8*)(src + vq * 8);
            int n0 = nh + vq * 8;
#pragma unroll
            for (int i = 0; i < 8; i++)
                shB[(n0 + i) * 136 + j] = f2bf(wj * bf2f((u16)vec[i]));
        }
    }
    __syncthreads();

    // ---- phase 3: Sc = UT.(BTw) -> bf16 [p][128]
    f32x4 acc3[4][2] = {};
#pragma unroll
    for (int ks = 0; ks < 4; ks++) {
        int kof = ks * 32;
        s16x8 ua[4], bb[2];
#pragma unroll
        for (int i = 0; i < 4; i++)
            ua[i] = *(const s16x8*)&shA[(i * 16 + lr) * 136 + kof + lk8];
#pragma unroll
        for (int jj = 0; jj < 2; jj++)
            bb[jj] = *(const s16x8*)&shB[(w * 32 + jj * 16 + lr) * 136 + kof + lk8];
#pragma unroll
        for (int i = 0; i < 4; i++)
#pragma unroll
            for (int jj = 0; jj < 2; jj++)
                acc3[i][jj] = __builtin_amdgcn_mfma_f32_16x16x32_bf16(ua[i], bb[jj], acc3[i][jj], 0, 0, 0);
    }
#pragma unroll
    for (int i = 0; i < 4; i++)
#pragma unroll
        for (int jj = 0; jj < 2; jj++) {
            int n = w * 32 + jj * 16 + (l & 15);
#pragma unroll
            for (int r = 0; r < 4; r++) {
                int p = i * 16 + (l >> 4) * 4 + r;
                scb16[(size_t)bhc * 8192 + (size_t)p * 128 + n] = f2bf(acc3[i][jj][r]);
            }
        }
}

// sequential chunk-state recurrence (bf16 in/out, f32 accumulate)
// 256 blocks x 256 thr: full CU coverage
__global__ __launch_bounds__(256) void k_states(u16* __restrict__ scb16,
                                                const float* __restrict__ elbuf) {
    int bh  = blockIdx.x >> 1;            // b*16+h
    int seg = blockIdx.x & 1;
    int t = threadIdx.x;
    float hreg[16];
#pragma unroll
    for (int j = 0; j < 16; j++) hreg[j] = 0.f;
    size_t o = (size_t)(seg * 256 + t) * 16;
    for (int c = 0; c < 8; c++) {
        int bhc = bh * 8 + c;
        float Tc = elbuf[(size_t)bhc * 128 + 127];
        u16* p = scb16 + (size_t)bhc * 8192 + o;
        s16x8 v0 = *(s16x8*)(p);
        s16x8 v1 = *(s16x8*)(p + 8);
        s16x8 o0, o1;
#pragma unroll
        for (int j = 0; j < 8; j++) {
            o0[j] = (short)f2bf(hreg[j]);
            o1[j] = (short)f2bf(hreg[8 + j]);
        }
        *(s16x8*)(p)     = o0;
        *(s16x8*)(p + 8) = o1;
#pragma unroll
        for (int j = 0; j < 8; j++) {
            hreg[j]     = fmaf(Tc, hreg[j],     bf2f((u16)v0[j]));
            hreg[8 + j] = fmaf(Tc, hreg[8 + j], bf2f((u16)v1[j]));
        }
    }
}

// ============ inter-chunk: pipelined stages + vector RMW epilogue ============
#define INT_STAGE(bf_, k0_) do {                                                \
    _Pragma("unroll")                                                           \
    for (int s_ = 0; s_ < 2; s_++) {                                            \
        int g_ = w * 2 + s_;                                                    \
        GLOAD_LDS16(bcbf + (row0 + g_ * 16 + lr) * 256 + 128 + (k0_) + lk8,     \
                    &CStg[bf_][g_ * 512]);                                      \
    }                                                                           \
    GLOAD_LDS16(scb16 + (size_t)bhc * 8192 + (size_t)(w * 16 + lr) * 128 + (k0_) + lk8, \
                &HStg[bf_][w * 512]);                                           \
    } while (0)

__global__ __launch_bounds__(256) void k_inter(
    const u16* __restrict__ xhbf, const u16* __restrict__ bcbf,
    const float* __restrict__ elbuf, const u16* __restrict__ scb16,
    const float* __restrict__ Dp, u16* __restrict__ y16) {
    int bid = blockIdx.x;
    int bhc = (bid & 7) * 128 + (bid >> 3);
    int c = bhc & 7, h = (bhc >> 3) & 15, b = bhc >> 7;
    const size_t row0 = (size_t)b * 1024 + c * 128;
    const int t = threadIdx.x, w = t >> 6, l = t & 63;
    const int wr = w >> 1, wc = w & 1;
    const int lr = l & 15, lk8 = (l >> 4) * 8;
    __shared__ __align__(16) u16 CStg[2][4096];
    __shared__ __align__(16) u16 HStg[2][2048];
    __shared__ __align__(16) float FY[64 * 68];
    __shared__ float el[128];
    float Dv = Dp[h];
    float elv = (t < 128) ? elbuf[(size_t)bhc * 128 + t] : 0.f;

    INT_STAGE(0, 0);
    INT_STAGE(1, 32);
    if (t < 128) el[t] = elv;

    f32x4 acc[4][2] = {};
    for (int ks = 0; ks < 4; ks++) {
        int cur = ks & 1;
        if (ks < 3) asm volatile("s_waitcnt vmcnt(3)" ::: "memory");
        else        asm volatile("s_waitcnt vmcnt(0)" ::: "memory");
        __builtin_amdgcn_s_barrier();
        s16x8 ca[4], hb[2];
#pragma unroll
        for (int i = 0; i < 4; i++)
            ca[i] = *(const s16x8*)&CStg[cur][(wr * 4 + i) * 512 + l * 8];
#pragma unroll
        for (int jj = 0; jj < 2; jj++)
            hb[jj] = *(const s16x8*)&HStg[cur][(wc * 2 + jj) * 512 + l * 8];
#pragma unroll
        for (int i = 0; i < 4; i++)
#pragma unroll
            for (int jj = 0; jj < 2; jj++)
                acc[i][jj] = __builtin_amdgcn_mfma_f32_16x16x32_bf16(ca[i], hb[jj], acc[i][jj], 0, 0, 0);
        __builtin_amdgcn_s_barrier();
        if (ks + 2 < 4) INT_STAGE(cur, (ks + 2) * 32);
    }

    // epilogue: chunked f32 repack (rows ch*64..) -> vector RMW
    for (int ch = 0; ch < 2; ch++) {
        if (wr == ch) {
#pragma unroll
            for (int i = 0; i < 4; i++)
#pragma unroll
                for (int jj = 0; jj < 2; jj++)
#pragma unroll
                    for (int r = 0; r < 4; r++) {
                        int rrow = i * 16 + (l >> 4) * 4 + r;   // 0..63
                        FY[rrow * 68 + wc * 32 + jj * 16 + (l & 15)] =
                            el[ch * 64 + rrow] * acc[i][jj][r];
                    }
        }
        __syncthreads();
#pragma unroll
        for (int it = 0; it < 2; it++) {
            int vv = it * 256 + t;            // 64*64/8 = 512 vectors
            int row = vv >> 3, col = (vv & 7) * 8;
            float4 f0 = *(const float4*)&FY[row * 68 + col];
            float4 f1 = *(const float4*)&FY[row * 68 + col + 4];
            size_t yo = (row0 + ch * 64 + row) * 1024 + h * 64 + col;
            s16x8 yv = *(const s16x8*)&y16[yo];
            s16x8 xv = *(const s16x8*)&xhbf[yo];
            s16x8 ov;
            const float* p0 = (const float*)&f0;
            const float* p1 = (const float*)&f1;
#pragma unroll
            for (int j = 0; j < 4; j++) {
                ov[j]     = (short)f2bf(bf2f((u16)yv[j])     + p0[j] + Dv * bf2f((u16)xv[j]));
                ov[4 + j] = (short)f2bf(bf2f((u16)yv[4 + j]) + p1[j] + Dv * bf2f((u16)xv[4 + j]));
            }
            *(s16x8*)&y16[yo] = ov;
        }
        __syncthreads();
    }
}

// ---------------- gate: ybf = bf16(rmsnorm(y * silu(z)) * norm_w) ----------------
__global__ __launch_bounds__(256) void k_gate(
    const u16* __restrict__ y16, const u16* __restrict__ zbf,
    const float* __restrict__ nw, u16* __restrict__ ybf) {
    __shared__ float sbuf[4];
    int bl = blockIdx.x;
    int t  = threadIdx.x;
    u16x4 yv4 = *(const u16x4*)(y16 + (size_t)bl * 1024 + t * 4);
    u16x4 zv4 = *(const u16x4*)(zbf + (size_t)bl * 1024 + t * 4);
    float4 gv;
    gv.x = bf2f(yv4.x) * siluf(bf2f(zv4.x));
    gv.y = bf2f(yv4.y) * siluf(bf2f(zv4.y));
    gv.z = bf2f(yv4.z) * siluf(bf2f(zv4.z));
    gv.w = bf2f(yv4.w) * siluf(bf2f(zv4.w));
    float q = gv.x * gv.x + gv.y * gv.y + gv.z * gv.z + gv.w * gv.w;
    for (int off = 32; off; off >>= 1) q += __shfl_xor(q, off, 64);
    int wid = t >> 6, lane = t & 63;
    if (lane == 0) sbuf[wid] = q;
    __syncthreads();
    float tot = sbuf[0] + sbuf[1] + sbuf[2] + sbuf[3];
    float scale = 1.0f / sqrtf(tot * (1.f / 1024.f) + EPS);
    float4 nv = *(const float4*)(nw + t * 4);
    float4 o;
    o.x = gv.x * scale * nv.x;
    o.y = gv.y * scale * nv.y;
    o.z = gv.z * scale * nv.z;
    o.w = gv.w * scale * nv.w;
    *(u16x4*)(ybf + (size_t)bl * 1024 + t * 4) = f2bf4(o);
}

// ---------------- pool stage 1 (bf16 input) ----------------
__global__ __launch_bounds__(256) void k_pool1(const u16* __restrict__ xbf,
                                               float* __restrict__ psum,
                                               float* __restrict__ pmax) {
    int blk = blockIdx.x;          // b*64 + lc
    int b = blk >> 6, lc = blk & 63;
    int t = threadIdx.x;
    const u16* px = xbf + (size_t)b * 524288 + (size_t)lc * 16 * 512;
    float s0 = 0.f, s1 = 0.f, m0 = -3.0e38f, m1 = -3.0e38f;
#pragma unroll
    for (int r = 0; r < 16; r++) {
        float v0 = bf2f(px[r * 512 + t]);
        float v1 = bf2f(px[r * 512 + t + 256]);
        s0 += v0; s1 += v1;
        m0 = fmaxf(m0, v0); m1 = fmaxf(m1, v1);
    }
    psum[(size_t)blk * 512 + t]       = s0;
    psum[(size_t)blk * 512 + t + 256] = s1;
    pmax[(size_t)blk * 512 + t]       = m0;
    pmax[(size_t)blk * 512 + t + 256] = m1;
}

// ---------------- pool stage 2 ----------------
__global__ __launch_bounds__(256) void k_pool2(const float* __restrict__ psum,
                                               const float* __restrict__ pmax,
                                               float* __restrict__ pooled) {
    int idx = blockIdx.x * 256 + threadIdx.x;   // 4096 exact
    int b = idx >> 9, d = idx & 511;
    float s = 0.f, m = -3.0e38f;
    for (int c = 0; c < 64; c++) {
        s += psum[((size_t)b * 64 + c) * 512 + d];
        m = fmaxf(m, pmax[((size_t)b * 64 + c) * 512 + d]);
    }
    pooled[idx] = 0.5f * (s * (1.f / 1024.f) + m);
}

// ---------------- small FC ----------------
template <int ACT>
__global__ void k_fc(const float* __restrict__ in, const float* __restrict__ W,
                     const float* __restrict__ bias, float* __restrict__ out,
                     int BN, int N, int K) {
    int idx = blockIdx.x * 64 + threadIdx.x;
    if (idx >= BN) return;
    int b = idx / N, n = idx % N;
    const float* a = in + (size_t)b * K;
    const float* w = W + (size_t)n * K;
    float acc = 0.f;
    for (int k = 0; k < K; k += 4) {
        float4 av = *(const float4*)(a + k);
        float4 wv = *(const float4*)(w + k);
        acc += av.x * wv.x + av.y * wv.y + av.z * wv.z + av.w * wv.w;
    }
    float v = acc + bias[n];
    if (ACT == 1) v = geluf(v);
    out[idx] = v;
}

extern "C" void kernel_launch(void* const* d_in, const int* in_sizes, int n_in,
                              void* d_out, int out_size, void* d_ws, size_t ws_size,
                              hipStream_t stream) {
    (void)in_sizes; (void)n_in; (void)out_size; (void)ws_size;
    const int*   tok        = (const int*)  d_in[0];
    const float* mask       = (const float*)d_in[1];
    const float* emb        = (const float*)d_in[2];
    const float* pos        = (const float*)d_in[3];
    const float* inp_w      = (const float*)d_in[4];
    const float* inp_b      = (const float*)d_in[5];
    const float* ln_g       = (const float*)d_in[6];
    const float* ln_b       = (const float*)d_in[7];
    const float* in_proj_w  = (const float*)d_in[8];
    const float* conv_w     = (const float*)d_in[9];
    const float* conv_b     = (const float*)d_in[10];
    const float* dt_bias    = (const float*)d_in[11];
    const float* A_log      = (const float*)d_in[12];
    const float* Dparam     = (const float*)d_in[13];
    const float* norm_w     = (const float*)d_in[14];
    const float* out_proj_w = (const float*)d_in[15];
    const float* pooler_w   = (const float*)d_in[16];
    const float* pooler_b   = (const float*)d_in[17];
    const float* cls_w1     = (const float*)d_in[18];
    const float* cls_b1     = (const float*)d_in[19];
    const float* cls_w2     = (const float*)d_in[20];
    const float* cls_b2     = (const float*)d_in[21];
    float* out = (float*)d_out;

    float* ws     = (float*)d_ws;
    float* x      = ws;                                // 8192*512 (prologue only)
    float* dt_raw = x + (size_t)8192 * 512;            // 8192*16
    float* elbuf  = dt_raw + (size_t)8192 * 16;        // 131072
    float* psum   = elbuf + 131072;                    // 262144
    float* pmax   = psum + 262144;                     // 262144
    float* pooled = pmax + 262144;                     // 4096
    float* pbuf   = pooled + 4096;                     // 4096
    float* cbuf   = pbuf + 4096;                       // 2048
    u16* x_bf    = (u16*)(cbuf + 2048);                // 8192*512 (bf16 residual)
    u16* z_bf    = x_bf + (size_t)8192 * 512;          // 8192*1024
    u16* xbc_in  = z_bf + (size_t)8192 * 1024;         // 8192*1280 (conv input bf16)
    u16* y_bf    = xbc_in + (size_t)8192 * 1280;       // 8192*1024 (gate out)
    u16* xhbf    = y_bf + (size_t)8192 * 1024;         // 8192*1024
    u16* bcbf    = xhbf + (size_t)8192 * 1024;         // 8192*256
    u16* y16     = bcbf + (size_t)8192 * 256;          // 8192*1024 (SSM out, bf16)
    u16* wip_bf  = y16 + (size_t)8192 * 1024;          // 4*2432*512
    u16* wop_bf  = wip_bf + (size_t)4 * 2432 * 512;    // 4*512*1024
    u16* winp_bf = wop_bf + (size_t)4 * 512 * 1024;    // 512*512
    // overlays in dead windows:
    u16* xe_bf   = (u16*)y16;                          // prologue only (y16 dead)
    u16* scb16   = xbc_in;                             // over xbc_in (dead between
                                                       // k_ssd and next in_proj)

    // merged weight casts + embedding (single dispatch)
    k_casts<<<11264, 256, 0, stream>>>(in_proj_w, out_proj_w, inp_w,
                                       wip_bf, wop_bf, winp_bf,
                                       tok, emb, pos, xe_bf);

    // x = embed @ inp_w^T + inp_b  (fp32, prologue only)
    k_gemm_mfma<1><<<256, 512, 0, stream>>>(xe_bf, winp_bf, inp_b, x, nullptr,
                                            nullptr, 8192, 512, 512, 4);
    // LN -> bf16 residual stream x_bf
    k_layernorm<<<8192, 128, 0, stream>>>(x, ln_g, ln_b, mask, x_bf);

    for (int i = 0; i < 4; i++) {
        // split in_proj: z_bf | xbc_in (bf16) | dt_raw (f32); 256x128 tile
        k_gemm_in<<<608, 512, 0, stream>>>(x_bf, wip_bf + (size_t)i * 2432 * 512,
                                           z_bf, xbc_in, dt_raw);
        k_conv<<<8192, 320, 0, stream>>>(xbc_in, conv_w + (size_t)i * 1280 * 4,
                                         conv_b + (size_t)i * 1280, xhbf, bcbf);
        k_ssd<<<1024, 256, 0, stream>>>(xhbf, bcbf, dt_raw, dt_bias + i * 16,
                                        A_log + i * 16, elbuf, y16, scb16);
        k_states<<<256, 256, 0, stream>>>(scb16, elbuf);
        k_inter<<<1024, 256, 0, stream>>>(xhbf, bcbf, elbuf, scb16,
                                          Dparam + (size_t)i * 16, y16);
        k_gate<<<8192, 256, 0, stream>>>(y16, z_bf, norm_w + (size_t)i * 1024, y_bf);
        // x_bf = bf16((x_bf + y @ out_proj_w[i]^T) * mask)   (bf16 residual RMW)
        k_gemm_mfma<2><<<256, 512, 0, stream>>>(y_bf, wop_bf + (size_t)i * 512 * 1024,
                                                nullptr, nullptr, x_bf, mask,
                                                8192, 512, 1024, 4);
    }

    k_pool1<<<512, 256, 0, stream>>>(x_bf, psum, pmax);
    k_pool2<<<16, 256, 0, stream>>>(psum, pmax, pooled);
    k_fc<1><<<64, 64, 0, stream>>>(pooled, pooler_w, pooler_b, pbuf, 8 * 512, 512, 512);
    k_fc<1><<<32, 64, 0, stream>>>(pbuf, cls_w1, cls_b1, cbuf, 8 * 256, 256, 512);
    k_fc<0><<<1, 64, 0, stream>>>(cbuf, cls_w2, cls_b2, out, 8 * 2, 2, 256);
}